// Round 12
// baseline (441.148 us; speedup 1.0000x reference)
//
#include <hip/hip_runtime.h>
#include <hip/hip_bf16.h>
#include <stdint.h>

#define D_ 1024
#define H_ 16
#define DH_ 64
#define S_ 2048
#define B_ 16
static constexpr float SCALE = 0.125f;  // 1/sqrt(64)

typedef __bf16 bf16_t;
typedef __bf16 bf16x8 __attribute__((ext_vector_type(8)));
typedef __bf16 bf16x4 __attribute__((ext_vector_type(4)));
typedef float  f32x4  __attribute__((ext_vector_type(4)));

__device__ __forceinline__ void llds16(const void* g, void* l) {
  __builtin_amdgcn_global_load_lds(
      (const __attribute__((address_space(1))) void*)g,
      (__attribute__((address_space(3))) void*)l, 16, 0, 0);
}

// ---------------------------------------------------------------------------
// hidden_states f32 -> bf16
// ---------------------------------------------------------------------------
__global__ __launch_bounds__(256)
void f32_to_bf16(const float* __restrict__ src, bf16_t* __restrict__ dst) {
  size_t base = ((size_t)blockIdx.x * 256 + threadIdx.x) * 8;
  f32x4 a = *(const f32x4*)&src[base];
  f32x4 b = *(const f32x4*)&src[base + 4];
  bf16x8 o;
#pragma unroll
  for (int i = 0; i < 4; ++i) { o[i] = (bf16_t)a[i]; o[4 + i] = (bf16_t)b[i]; }
  *(bf16x8*)&dst[base] = o;
}

// ---------------------------------------------------------------------------
// 3x 1024x1024 f32 -> bf16 transpose in one launch: dst[n][k] = src[k][n]
// ---------------------------------------------------------------------------
__global__ __launch_bounds__(256)
void transpose1024_all(const float* __restrict__ s0, const float* __restrict__ s1,
                       const float* __restrict__ s2, bf16_t* __restrict__ d0,
                       bf16_t* __restrict__ d1, bf16_t* __restrict__ d2) {
  __shared__ bf16_t t[64][65];
  const float* src = (blockIdx.z == 0) ? s0 : (blockIdx.z == 1) ? s1 : s2;
  bf16_t* dst      = (blockIdx.z == 0) ? d0 : (blockIdx.z == 1) ? d1 : d2;
  const int n0 = blockIdx.x * 64, k0 = blockIdx.y * 64;
  const int r = threadIdx.x >> 4, c4 = (threadIdx.x & 15) * 4;
#pragma unroll
  for (int p = 0; p < 4; ++p) {
    int row = p * 16 + r;
    f32x4 f = *(const f32x4*)&src[(size_t)(k0 + row) * 1024 + n0 + c4];
#pragma unroll
    for (int i = 0; i < 4; ++i) t[row][c4 + i] = (bf16_t)f[i];
  }
  __syncthreads();
#pragma unroll
  for (int p = 0; p < 4; ++p) {
    int row = p * 16 + r;
    bf16x4 v;
#pragma unroll
    for (int i = 0; i < 4; ++i) v[i] = t[c4 + i][row];
    *(bf16x4*)&dst[(size_t)(n0 + row) * 1024 + k0 + c4] = v;
  }
}

// [1024][16] f32 -> [16][1024] bf16, both Wqa and Wka in one launch
__global__ __launch_bounds__(256)
void transpose_small_all(const float* __restrict__ sa, const float* __restrict__ sb,
                         bf16_t* __restrict__ da, bf16_t* __restrict__ db) {
  int g = blockIdx.x * 256 + threadIdx.x;
  const float* src = (g < 1024) ? sa : sb;
  bf16_t* dst      = (g < 1024) ? da : db;
  int k = g & 1023;
#pragma unroll
  for (int h = 0; h < H_; ++h) dst[h * 1024 + k] = (bf16_t)src[k * H_ + h];
}

// ---------------------------------------------------------------------------
// GEMM: C[M][1024] = A[M][1024] @ BT[1024][1024]^T + bias (+epilogue)
// 128x128 tile, BK=64 (halves barrier-drain count vs BK=32 — the diagnosed
// limiter: MfmaUtil+VALUBusy=46%, conflict-fix was perf-neutral -> stalls
// dominate). 8-slot rotation swizzle (2-way reads = free). Epilogue LDS
// overlays the dead A/B tile buffers (est 17.4KB < 32KB) -> LDS stays 32KB.
// MODE 0: A = bf16 hsb                             -> bf16 (mixed_q)
// MODE 1: A = bf16 hsb, *pscale[b][col]            -> bf16 (mixed_qk)
// MODE 2: A = bf16 mq * pkA[b][k] (fused), +resid  -> f32 (final output)
// ---------------------------------------------------------------------------
template <int MODE>
__global__ __launch_bounds__(256, 2)
void gemm_bt(const bf16_t* __restrict__ A, const bf16_t* __restrict__ BT,
             const float* __restrict__ bias, void* __restrict__ Cout,
             const float* __restrict__ pscale, const bf16_t* __restrict__ resid,
             const float* __restrict__ pkA) {
  constexpr int K = 1024, N = 1024;
  __shared__ __align__(16) bf16_t lds2[2][128 * 64];  // [0]=A tile, [1]=B tile
  bf16_t* lA = &lds2[0][0];
  bf16_t* lB = &lds2[1][0];
  const int tid = threadIdx.x;
  const int lane = tid & 63, wid = tid >> 6;
  const int wr = wid >> 1, wc = wid & 1;

  // XCD swizzle: nwg=2048, 2048%8==0
  const int wgid = (blockIdx.x & 7) * 256 + (blockIdx.x >> 3);
  const int m0 = (wgid >> 3) * 128;
  const int n0 = (wgid & 7) * 128;
  const int b = m0 / S_;

  const int ar = lane & 15;
  const int kq = lane >> 4;   // 16B k-chunk within a 32-k step (0..3)

  // staging map: 4 chunks/thread/matrix; chunk c -> row c>>3, slot c&7;
  // slot s of row r holds global k-chunk (s - (r&7)) & 7 (involution rotation)
  int rowc[4], colc[4], dstoff[4];
#pragma unroll
  for (int j = 0; j < 4; ++j) {
    int c = j * 256 + tid;          // 0..1023
    int row = c >> 3, s = c & 7;
    rowc[j] = row;
    colc[j] = (((s - (row & 7)) & 7) << 3);
    dstoff[j] = c * 8;
  }

  f32x4 acc[4][4] = {};

  for (int k0 = 0; k0 < K; k0 += 64) {
#pragma unroll
    for (int j = 0; j < 4; ++j) {
      const bf16_t* gb = BT + (size_t)(n0 + rowc[j]) * K + k0 + colc[j];
      llds16(gb, lB + dstoff[j]);
      if (MODE == 2) {
        // fused weighted: A-chunk = mq * pk[b][k], reg-staged
        bf16x8 v = *(const bf16x8*)(A + (size_t)(m0 + rowc[j]) * K + k0 + colc[j]);
        const float* pkp = pkA + b * D_ + k0 + colc[j];
        f32x4 p0 = *(const f32x4*)pkp;
        f32x4 p1 = *(const f32x4*)(pkp + 4);
        bf16x8 o;
#pragma unroll
        for (int i = 0; i < 4; ++i) {
          o[i]     = (bf16_t)((float)v[i] * p0[i]);
          o[4 + i] = (bf16_t)((float)v[4 + i] * p1[i]);
        }
        *(bf16x8*)&lA[dstoff[j]] = o;
      } else {
        const bf16_t* ga = A + (size_t)(m0 + rowc[j]) * K + k0 + colc[j];
        llds16(ga, lA + dstoff[j]);
      }
    }
    __syncthreads();
    // two 32-k sub-phases between the same barrier pair
#pragma unroll
    for (int h = 0; h < 2; ++h) {
      bf16x8 af[4], bg[4];
#pragma unroll
      for (int m = 0; m < 4; ++m) {
        int r = wr * 64 + m * 16 + ar;
        int slot = ((h * 4 + kq) + (r & 7)) & 7;
        af[m] = *(const bf16x8*)&lA[r * 64 + slot * 8];
      }
#pragma unroll
      for (int n = 0; n < 4; ++n) {
        int r = wc * 64 + n * 16 + ar;
        int slot = ((h * 4 + kq) + (r & 7)) & 7;
        bg[n] = *(const bf16x8*)&lB[r * 64 + slot * 8];
      }
#pragma unroll
      for (int m = 0; m < 4; ++m)
#pragma unroll
        for (int n = 0; n < 4; ++n)
          acc[m][n] = __builtin_amdgcn_mfma_f32_16x16x32_bf16(af[m], bg[n], acc[m][n], 0, 0, 0);
    }
    __syncthreads();
  }

  // ----- epilogue: LDS-staged coalesced stores; est overlays dead tiles -----
  float* st = (float*)&lds2[0][0] + wid * (16 * 68);
  const int erow = lane >> 2;          // 0..15
  const int ecol = (lane & 3) * 16;    // 0,16,32,48
  const int gcb = n0 + wc * 64;        // wave col base
  const int qrow = (lane >> 4) * 4;
  const int qcol = lane & 15;
  f32x4 bb[4], ps[4];
#pragma unroll
  for (int q = 0; q < 4; ++q) bb[q] = *(const f32x4*)&bias[gcb + ecol + q * 4];
  if (MODE == 1) {
#pragma unroll
    for (int q = 0; q < 4; ++q) ps[q] = *(const f32x4*)&pscale[b * D_ + gcb + ecol + q * 4];
  }
#pragma unroll
  for (int m = 0; m < 4; ++m) {
#pragma unroll
    for (int n = 0; n < 4; ++n)
#pragma unroll
      for (int j = 0; j < 4; ++j)
        st[(qrow + j) * 68 + n * 16 + qcol] = acc[m][n][j];
    asm volatile("s_waitcnt lgkmcnt(0)" ::: "memory");
    __builtin_amdgcn_sched_barrier(0);
    const int grow = m0 + wr * 64 + m * 16 + erow;
    f32x4 v[4];
#pragma unroll
    for (int q = 0; q < 4; ++q) v[q] = *(f32x4*)&st[erow * 68 + ecol + q * 4];
#pragma unroll
    for (int q = 0; q < 4; ++q)
#pragma unroll
      for (int i = 0; i < 4; ++i) v[q][i] += bb[q][i];
    if (MODE == 1) {
#pragma unroll
      for (int q = 0; q < 4; ++q)
#pragma unroll
        for (int i = 0; i < 4; ++i) v[q][i] *= ps[q][i];
    }
    if (MODE == 2) {
      bf16x8 r0 = *(const bf16x8*)&resid[(size_t)grow * N + gcb + ecol];
      bf16x8 r1 = *(const bf16x8*)&resid[(size_t)grow * N + gcb + ecol + 8];
#pragma unroll
      for (int i = 0; i < 4; ++i) { v[0][i] += (float)r0[i]; v[1][i] += (float)r0[4 + i]; }
#pragma unroll
      for (int i = 0; i < 4; ++i) { v[2][i] += (float)r1[i]; v[3][i] += (float)r1[4 + i]; }
      float* op = (float*)Cout + (size_t)grow * N + gcb + ecol;
#pragma unroll
      for (int q = 0; q < 4; ++q) *(f32x4*)&op[q * 4] = v[q];
    } else {
      bf16x8 o0, o1;
#pragma unroll
      for (int i = 0; i < 4; ++i) { o0[i] = (bf16_t)v[0][i]; o0[4 + i] = (bf16_t)v[1][i]; }
#pragma unroll
      for (int i = 0; i < 4; ++i) { o1[i] = (bf16_t)v[2][i]; o1[4 + i] = (bf16_t)v[3][i]; }
      bf16_t* op = (bf16_t*)Cout + (size_t)grow * N + gcb + ecol;
      *(bf16x8*)&op[0] = o0;
      *(bf16x8*)&op[8] = o1;
    }
  }
}

// ---------------------------------------------------------------------------
// scores[b*H+h][s] = (X[b,s,:] . WaT[h,:] + ba[h]) * SCALE + mask[b][s]
// ---------------------------------------------------------------------------
__global__ __launch_bounds__(256)
void score_kernel(const bf16_t* __restrict__ X, const bf16_t* __restrict__ WaT,
                  const float* __restrict__ ba, const float* __restrict__ mask,
                  float* __restrict__ scores) {
  const int lane = threadIdx.x & 63, wid = threadIdx.x >> 6;
  const int m0 = blockIdx.x * 64 + wid * 16;
  const int ar = lane & 15, ak = (lane >> 4) * 8;
  f32x4 acc = {};
  for (int k0 = 0; k0 < D_; k0 += 32) {
    bf16x8 a = *(const bf16x8*)&X[(size_t)(m0 + ar) * D_ + k0 + ak];
    bf16x8 b = *(const bf16x8*)&WaT[(size_t)ar * D_ + k0 + ak];
    acc = __builtin_amdgcn_mfma_f32_16x16x32_bf16(a, b, acc, 0, 0, 0);
  }
  const int h = lane & 15;
  const int srow = m0 + (lane >> 4) * 4;
  const int bb = srow / S_;
  const int s0 = srow - bb * S_;
  const float bah = ba[h];
  f32x4 mv = *(const f32x4*)&mask[(size_t)bb * S_ + s0];
  f32x4 outv;
#pragma unroll
  for (int j = 0; j < 4; ++j)
    outv[j] = (acc[j] + bah) * SCALE + mv[j];
  *(f32x4*)&scores[((size_t)(bb * H_ + h)) * S_ + s0] = outv;
}

// ---------------------------------------------------------------------------
// softmax over each scores row -> normalized weights
// ---------------------------------------------------------------------------
__global__ __launch_bounds__(256)
void softmax_rows(const float* __restrict__ scores, float* __restrict__ wout) {
  __shared__ float rA[4], rB[4];
  const int tid = threadIdx.x, lane = tid & 63, wid = tid >> 6;
  const float* srow = scores + (size_t)blockIdx.x * S_;
  float* wrow = wout + (size_t)blockIdx.x * S_;
  f32x4 v0 = *(const f32x4*)&srow[tid * 4];
  f32x4 v1 = *(const f32x4*)&srow[1024 + tid * 4];
  float mx = fmaxf(fmaxf(fmaxf(v0[0], v0[1]), fmaxf(v0[2], v0[3])),
                   fmaxf(fmaxf(v1[0], v1[1]), fmaxf(v1[2], v1[3])));
#pragma unroll
  for (int o = 32; o; o >>= 1) mx = fmaxf(mx, __shfl_xor(mx, o));
  if (lane == 0) rA[wid] = mx;
  __syncthreads();
  mx = fmaxf(fmaxf(rA[0], rA[1]), fmaxf(rA[2], rA[3]));
  float sum = 0.f;
#pragma unroll
  for (int i = 0; i < 4; ++i) { v0[i] = __expf(v0[i] - mx); sum += v0[i]; }
#pragma unroll
  for (int i = 0; i < 4; ++i) { v1[i] = __expf(v1[i] - mx); sum += v1[i]; }
#pragma unroll
  for (int o = 32; o; o >>= 1) sum += __shfl_xor(sum, o);
  if (lane == 0) rB[wid] = sum;
  __syncthreads();
  sum = rB[0] + rB[1] + rB[2] + rB[3];
  const float inv = 1.0f / sum;
#pragma unroll
  for (int i = 0; i < 4; ++i) { v0[i] *= inv; v1[i] *= inv; }
  *(f32x4*)&wrow[tid * 4] = v0;
  *(f32x4*)&wrow[1024 + tid * 4] = v1;
}

// ---------------------------------------------------------------------------
// pool partials over 32-row chunks (coalesced bf16x8)
// ---------------------------------------------------------------------------
__global__ __launch_bounds__(256)
void pool_partial(const bf16_t* __restrict__ X, const float* __restrict__ w,
                  float* __restrict__ partials) {
  __shared__ float sm[2][1024];
  const int tid = threadIdx.x;
  const int chunk = blockIdx.x, b = blockIdx.y;
  const int s0 = chunk * 32;
  const int dc = (tid & 127) * 8;
  const int sp = tid >> 7;
  const int h = dc >> 6;
  const float* wrow = w + ((size_t)b * H_ + h) * S_ + s0;
  const bf16_t* Xb = X + ((size_t)b * S_ + s0) * D_ + dc;
  float acc[8] = {};
  for (int s = sp; s < 32; s += 2) {
    bf16x8 xv = *(const bf16x8*)&Xb[(size_t)s * D_];
    float wt = wrow[s];
#pragma unroll
    for (int j = 0; j < 8; ++j) acc[j] += wt * (float)xv[j];
  }
#pragma unroll
  for (int j = 0; j < 8; ++j) sm[sp][dc + j] = acc[j];
  __syncthreads();
  const int d0 = tid * 4;
  f32x4 r;
#pragma unroll
  for (int j = 0; j < 4; ++j) r[j] = sm[0][d0 + j] + sm[1][d0 + j];
  *(f32x4*)&partials[((size_t)chunk * B_ + b) * D_ + d0] = r;
}

__global__ __launch_bounds__(256)
void pool_reduce(const float* __restrict__ partials, float* __restrict__ pooled) {
  const int idx = blockIdx.x * 256 + threadIdx.x;
  float s = 0.f;
#pragma unroll 8
  for (int c = 0; c < 64; ++c) s += partials[(size_t)c * (B_ * D_) + idx];
  pooled[idx] = s;
}

// ---------------------------------------------------------------------------
extern "C" void kernel_launch(void* const* d_in, const int* in_sizes, int n_in,
                              void* d_out, int out_size, void* d_ws, size_t ws_size,
                              hipStream_t stream) {
  const float* hs   = (const float*)d_in[0];
  const float* mask = (const float*)d_in[1];
  const float* Wq   = (const float*)d_in[2];
  const float* bq   = (const float*)d_in[3];
  const float* Wqa  = (const float*)d_in[4];
  const float* bqa  = (const float*)d_in[5];
  const float* Wk   = (const float*)d_in[6];
  const float* bk   = (const float*)d_in[7];
  const float* Wka  = (const float*)d_in[8];
  const float* bka  = (const float*)d_in[9];
  const float* Wt   = (const float*)d_in[10];
  const float* bt   = (const float*)d_in[11];

  char* ws = (char*)d_ws;
  float*  pq    = (float*)(ws + (64u << 10));
  float*  pk    = (float*)(ws + (128u << 10));
  bf16_t* WqaT  = (bf16_t*)(ws + (1u << 20));
  bf16_t* WkaT  = (bf16_t*)(ws + (1u << 20) + 32768);
  bf16_t* WqT   = (bf16_t*)(ws + (2u << 20));
  bf16_t* WkT   = (bf16_t*)(ws + (4u << 20));
  bf16_t* WtT   = (bf16_t*)(ws + (6u << 20));
  bf16_t* hsb   = (bf16_t*)(ws + (8u << 20));
  bf16_t* mq    = (bf16_t*)(ws + (8u << 20) + ((size_t)64 << 20));
  bf16_t* mqk   = (bf16_t*)(ws + (8u << 20) + ((size_t)128 << 20));
  float* scores = (float*)(ws + (8u << 20) + ((size_t)192 << 20));
  float* wsm    = (float*)(ws + (8u << 20) + ((size_t)194 << 20));
  float* parts  = (float*)(ws + (8u << 20) + ((size_t)196 << 20));

  // prep
  f32_to_bf16<<<16384, 256, 0, stream>>>(hs, hsb);
  transpose1024_all<<<dim3(16, 16, 3), 256, 0, stream>>>(Wq, Wk, Wt, WqT, WkT, WtT);
  transpose_small_all<<<8, 256, 0, stream>>>(Wqa, Wka, WqaT, WkaT);

  // mixed_q = hsb @ Wq + bq
  gemm_bt<0><<<2048, 256, 0, stream>>>(hsb, WqT, bq, mq, nullptr, nullptr, nullptr);

  score_kernel<<<512, 256, 0, stream>>>(mq, WqaT, bqa, mask, scores);
  softmax_rows<<<256, 256, 0, stream>>>(scores, wsm);
  pool_partial<<<dim3(64, 16), 256, 0, stream>>>(mq, wsm, parts);
  pool_reduce<<<64, 256, 0, stream>>>(parts, pq);

  // mixed_qk = (hsb @ Wk + bk) * pooled_q
  gemm_bt<1><<<2048, 256, 0, stream>>>(hsb, WkT, bk, mqk, pq, nullptr, nullptr);

  score_kernel<<<512, 256, 0, stream>>>(mqk, WkaT, bka, mask, scores);
  softmax_rows<<<256, 256, 0, stream>>>(scores, wsm);
  pool_partial<<<dim3(64, 16), 256, 0, stream>>>(mqk, wsm, parts);
  pool_reduce<<<64, 256, 0, stream>>>(parts, pk);

  // out = (mq * pk) @ Wt + bt + mixed_q   (weighted fused into A-staging)
  gemm_bt<2><<<2048, 256, 0, stream>>>(mq, WtT, bt, d_out, nullptr, mq, pk);
}

// Round 13
// 400.189 us; speedup vs baseline: 1.1023x; 1.1023x over previous
//
#include <hip/hip_runtime.h>
#include <hip/hip_bf16.h>
#include <stdint.h>

#define D_ 1024
#define H_ 16
#define DH_ 64
#define S_ 2048
#define B_ 16
static constexpr float SCALE = 0.125f;  // 1/sqrt(64)

typedef __bf16 bf16_t;
typedef __bf16 bf16x8 __attribute__((ext_vector_type(8)));
typedef __bf16 bf16x4 __attribute__((ext_vector_type(4)));
typedef float  f32x4  __attribute__((ext_vector_type(4)));

__device__ __forceinline__ void llds16(const void* g, void* l) {
  __builtin_amdgcn_global_load_lds(
      (const __attribute__((address_space(1))) void*)g,
      (__attribute__((address_space(3))) void*)l, 16, 0, 0);
}

// ---------------------------------------------------------------------------
// hidden_states f32 -> bf16
// ---------------------------------------------------------------------------
__global__ __launch_bounds__(256)
void f32_to_bf16(const float* __restrict__ src, bf16_t* __restrict__ dst) {
  size_t base = ((size_t)blockIdx.x * 256 + threadIdx.x) * 8;
  f32x4 a = *(const f32x4*)&src[base];
  f32x4 b = *(const f32x4*)&src[base + 4];
  bf16x8 o;
#pragma unroll
  for (int i = 0; i < 4; ++i) { o[i] = (bf16_t)a[i]; o[4 + i] = (bf16_t)b[i]; }
  *(bf16x8*)&dst[base] = o;
}

// ---------------------------------------------------------------------------
// 3x 1024x1024 f32 -> bf16 transpose in one launch: dst[n][k] = src[k][n]
// ---------------------------------------------------------------------------
__global__ __launch_bounds__(256)
void transpose1024_all(const float* __restrict__ s0, const float* __restrict__ s1,
                       const float* __restrict__ s2, bf16_t* __restrict__ d0,
                       bf16_t* __restrict__ d1, bf16_t* __restrict__ d2) {
  __shared__ bf16_t t[64][65];
  const float* src = (blockIdx.z == 0) ? s0 : (blockIdx.z == 1) ? s1 : s2;
  bf16_t* dst      = (blockIdx.z == 0) ? d0 : (blockIdx.z == 1) ? d1 : d2;
  const int n0 = blockIdx.x * 64, k0 = blockIdx.y * 64;
  const int r = threadIdx.x >> 4, c4 = (threadIdx.x & 15) * 4;
#pragma unroll
  for (int p = 0; p < 4; ++p) {
    int row = p * 16 + r;
    f32x4 f = *(const f32x4*)&src[(size_t)(k0 + row) * 1024 + n0 + c4];
#pragma unroll
    for (int i = 0; i < 4; ++i) t[row][c4 + i] = (bf16_t)f[i];
  }
  __syncthreads();
#pragma unroll
  for (int p = 0; p < 4; ++p) {
    int row = p * 16 + r;
    bf16x4 v;
#pragma unroll
    for (int i = 0; i < 4; ++i) v[i] = t[c4 + i][row];
    *(bf16x4*)&dst[(size_t)(n0 + row) * 1024 + k0 + c4] = v;
  }
}

// [1024][16] f32 -> [16][1024] bf16, both Wqa and Wka in one launch
__global__ __launch_bounds__(256)
void transpose_small_all(const float* __restrict__ sa, const float* __restrict__ sb,
                         bf16_t* __restrict__ da, bf16_t* __restrict__ db) {
  int g = blockIdx.x * 256 + threadIdx.x;
  const float* src = (g < 1024) ? sa : sb;
  bf16_t* dst      = (g < 1024) ? da : db;
  int k = g & 1023;
#pragma unroll
  for (int h = 0; h < H_; ++h) dst[h * 1024 + k] = (bf16_t)src[k * H_ + h];
}

// ---------------------------------------------------------------------------
// Dual-N GEMM: one kernel computes BOTH mixed_q = hs@Wq+bq and
// mixed_k = hs@Wk+bk (the *pq modulate is deferred to consumers).
// Each A-panel staged once serves 16 N-blocks (8 Wq + 8 Wk): A HBM fetch
// halved vs two separate GEMMs. r11 inner loop (m97 128x128/BK=32,
// slot-rotation swizzle=0 conflicts, staged epilogue, (256,2)) unchanged.
// ---------------------------------------------------------------------------
__global__ __launch_bounds__(256, 2)
void gemm_qk(const bf16_t* __restrict__ A, const bf16_t* __restrict__ WqT,
             const bf16_t* __restrict__ WkT, const float* __restrict__ bq,
             const float* __restrict__ bk, bf16_t* __restrict__ mq,
             bf16_t* __restrict__ mk) {
  constexpr int K = 1024, N = 1024;
  __shared__ __align__(16) bf16_t lA[128 * 32];
  __shared__ __align__(16) bf16_t lB[128 * 32];
  __shared__ __align__(16) float est[4][16 * 68];
  const int tid = threadIdx.x;
  const int lane = tid & 63, wid = tid >> 6;
  const int wr = wid >> 1, wc = wid & 1;

  // XCD swizzle: nwg=4096, 4096%8==0 -> 512 contiguous ids per XCD
  // = 32 M-panels x 16 N-blocks; A-panel fetched by a single XCD.
  const int wgid = (blockIdx.x & 7) * 512 + (blockIdx.x >> 3);
  const int m0 = (wgid >> 4) * 128;
  const int nsel = wgid & 15;            // 0..7 -> Wq half, 8..15 -> Wk half
  const int n0 = (nsel & 7) * 128;
  const bf16_t* BT = (nsel < 8) ? WqT : WkT;
  const float* bias = (nsel < 8) ? bq : bk;
  bf16_t* Cout = (nsel < 8) ? mq : mk;

  const int ar = lane & 15;
  const int kq = lane >> 4;

  // staging chunk map; lds row r slot s holds global k-chunk (s-(r>>1))&3
  int rowc[2], colc[2], dstoff[2];
#pragma unroll
  for (int j = 0; j < 2; ++j) {
    int c = j * 256 + tid;
    int row = c >> 2, s = c & 3;
    rowc[j] = row;
    colc[j] = (((s - (row >> 1)) & 3) << 3);
    dstoff[j] = c * 8;
  }

  f32x4 acc[4][4] = {};

  for (int k0 = 0; k0 < K; k0 += 32) {
#pragma unroll
    for (int j = 0; j < 2; ++j) {
      llds16(BT + (size_t)(n0 + rowc[j]) * K + k0 + colc[j], lB + dstoff[j]);
      llds16(A + (size_t)(m0 + rowc[j]) * K + k0 + colc[j], lA + dstoff[j]);
    }
    __syncthreads();
    bf16x8 af[4], bg[4];
#pragma unroll
    for (int m = 0; m < 4; ++m) {
      int r = wr * 64 + m * 16 + ar;
      af[m] = *(const bf16x8*)&lA[r * 32 + (((kq + (r >> 1)) & 3) << 3)];
    }
#pragma unroll
    for (int n = 0; n < 4; ++n) {
      int r = wc * 64 + n * 16 + ar;
      bg[n] = *(const bf16x8*)&lB[r * 32 + (((kq + (r >> 1)) & 3) << 3)];
    }
#pragma unroll
    for (int m = 0; m < 4; ++m)
#pragma unroll
      for (int n = 0; n < 4; ++n)
        acc[m][n] = __builtin_amdgcn_mfma_f32_16x16x32_bf16(af[m], bg[n], acc[m][n], 0, 0, 0);
    __syncthreads();
  }

  // epilogue: LDS-staged coalesced bf16 stores (+bias)
  float* st = est[wid];
  const int erow = lane >> 2;
  const int ecol = (lane & 3) * 16;
  const int gcb = n0 + wc * 64;
  const int qrow = (lane >> 4) * 4;
  const int qcol = lane & 15;
  f32x4 bb[4];
#pragma unroll
  for (int q = 0; q < 4; ++q) bb[q] = *(const f32x4*)&bias[gcb + ecol + q * 4];
#pragma unroll
  for (int m = 0; m < 4; ++m) {
#pragma unroll
    for (int n = 0; n < 4; ++n)
#pragma unroll
      for (int j = 0; j < 4; ++j)
        st[(qrow + j) * 68 + n * 16 + qcol] = acc[m][n][j];
    asm volatile("s_waitcnt lgkmcnt(0)" ::: "memory");
    __builtin_amdgcn_sched_barrier(0);
    const int grow = m0 + wr * 64 + m * 16 + erow;
    f32x4 v[4];
#pragma unroll
    for (int q = 0; q < 4; ++q) v[q] = *(f32x4*)&st[erow * 68 + ecol + q * 4];
#pragma unroll
    for (int q = 0; q < 4; ++q)
#pragma unroll
      for (int i = 0; i < 4; ++i) v[q][i] += bb[q][i];
    bf16x8 o0, o1;
#pragma unroll
    for (int i = 0; i < 4; ++i) { o0[i] = (bf16_t)v[0][i]; o0[4 + i] = (bf16_t)v[1][i]; }
#pragma unroll
    for (int i = 0; i < 4; ++i) { o1[i] = (bf16_t)v[2][i]; o1[4 + i] = (bf16_t)v[3][i]; }
    bf16_t* op = Cout + (size_t)grow * N + gcb + ecol;
    *(bf16x8*)&op[0] = o0;
    *(bf16x8*)&op[8] = o1;
  }
}

// ---------------------------------------------------------------------------
// Final GEMM: out = (mq * pkA) @ WtT + bt + resid(mq)  -> f32
// r11 MODE2 config: reg-staged fused-weighted A, gload_lds B.
// ---------------------------------------------------------------------------
__global__ __launch_bounds__(256, 2)
void gemm_out(const bf16_t* __restrict__ A, const bf16_t* __restrict__ BT,
              const float* __restrict__ bias, float* __restrict__ Cout,
              const bf16_t* __restrict__ resid, const float* __restrict__ pkA) {
  constexpr int K = 1024, N = 1024;
  __shared__ __align__(16) bf16_t lA[128 * 32];
  __shared__ __align__(16) bf16_t lB[128 * 32];
  __shared__ __align__(16) float est[4][16 * 68];
  const int tid = threadIdx.x;
  const int lane = tid & 63, wid = tid >> 6;
  const int wr = wid >> 1, wc = wid & 1;

  const int wgid = (blockIdx.x & 7) * 256 + (blockIdx.x >> 3);
  const int m0 = (wgid >> 3) * 128;
  const int n0 = (wgid & 7) * 128;
  const int b = m0 / S_;

  const int ar = lane & 15;
  const int kq = lane >> 4;

  int rowc[2], colc[2], dstoff[2];
#pragma unroll
  for (int j = 0; j < 2; ++j) {
    int c = j * 256 + tid;
    int row = c >> 2, s = c & 3;
    rowc[j] = row;
    colc[j] = (((s - (row >> 1)) & 3) << 3);
    dstoff[j] = c * 8;
  }

  f32x4 acc[4][4] = {};

  for (int k0 = 0; k0 < K; k0 += 32) {
#pragma unroll
    for (int j = 0; j < 2; ++j) {
      llds16(BT + (size_t)(n0 + rowc[j]) * K + k0 + colc[j], lB + dstoff[j]);
      bf16x8 v = *(const bf16x8*)(A + (size_t)(m0 + rowc[j]) * K + k0 + colc[j]);
      const float* pkp = pkA + b * D_ + k0 + colc[j];
      f32x4 p0 = *(const f32x4*)pkp;
      f32x4 p1 = *(const f32x4*)(pkp + 4);
      bf16x8 o;
#pragma unroll
      for (int i = 0; i < 4; ++i) {
        o[i]     = (bf16_t)((float)v[i] * p0[i]);
        o[4 + i] = (bf16_t)((float)v[4 + i] * p1[i]);
      }
      *(bf16x8*)&lA[dstoff[j]] = o;
    }
    __syncthreads();
    bf16x8 af[4], bg[4];
#pragma unroll
    for (int m = 0; m < 4; ++m) {
      int r = wr * 64 + m * 16 + ar;
      af[m] = *(const bf16x8*)&lA[r * 32 + (((kq + (r >> 1)) & 3) << 3)];
    }
#pragma unroll
    for (int n = 0; n < 4; ++n) {
      int r = wc * 64 + n * 16 + ar;
      bg[n] = *(const bf16x8*)&lB[r * 32 + (((kq + (r >> 1)) & 3) << 3)];
    }
#pragma unroll
    for (int m = 0; m < 4; ++m)
#pragma unroll
      for (int n = 0; n < 4; ++n)
        acc[m][n] = __builtin_amdgcn_mfma_f32_16x16x32_bf16(af[m], bg[n], acc[m][n], 0, 0, 0);
    __syncthreads();
  }

  float* st = est[wid];
  const int erow = lane >> 2;
  const int ecol = (lane & 3) * 16;
  const int gcb = n0 + wc * 64;
  const int qrow = (lane >> 4) * 4;
  const int qcol = lane & 15;
  f32x4 bb[4];
#pragma unroll
  for (int q = 0; q < 4; ++q) bb[q] = *(const f32x4*)&bias[gcb + ecol + q * 4];
#pragma unroll
  for (int m = 0; m < 4; ++m) {
#pragma unroll
    for (int n = 0; n < 4; ++n)
#pragma unroll
      for (int j = 0; j < 4; ++j)
        st[(qrow + j) * 68 + n * 16 + qcol] = acc[m][n][j];
    asm volatile("s_waitcnt lgkmcnt(0)" ::: "memory");
    __builtin_amdgcn_sched_barrier(0);
    const int grow = m0 + wr * 64 + m * 16 + erow;
    f32x4 v[4];
#pragma unroll
    for (int q = 0; q < 4; ++q) v[q] = *(f32x4*)&st[erow * 68 + ecol + q * 4];
#pragma unroll
    for (int q = 0; q < 4; ++q)
#pragma unroll
      for (int i = 0; i < 4; ++i) v[q][i] += bb[q][i];
    bf16x8 r0 = *(const bf16x8*)&resid[(size_t)grow * N + gcb + ecol];
    bf16x8 r1 = *(const bf16x8*)&resid[(size_t)grow * N + gcb + ecol + 8];
#pragma unroll
    for (int i = 0; i < 4; ++i) { v[0][i] += (float)r0[i]; v[1][i] += (float)r0[4 + i]; }
#pragma unroll
    for (int i = 0; i < 4; ++i) { v[2][i] += (float)r1[i]; v[3][i] += (float)r1[4 + i]; }
    float* op = Cout + (size_t)grow * N + gcb + ecol;
#pragma unroll
    for (int q = 0; q < 4; ++q) *(f32x4*)&op[q * 4] = v[q];
  }
}

// ---------------------------------------------------------------------------
// scores[b*H+h][s] = ((X .* pq?) [b,s,:] . WaT[h,:] + ba[h]) * SCALE + mask
// SCALED=1: A-fragment = bf16(X * pq[b,k]) on the fly (mixed_qk never stored)
// ---------------------------------------------------------------------------
template <int SCALED>
__global__ __launch_bounds__(256)
void score_kernel(const bf16_t* __restrict__ X, const bf16_t* __restrict__ WaT,
                  const float* __restrict__ ba, const float* __restrict__ mask,
                  const float* __restrict__ pq, float* __restrict__ scores) {
  const int lane = threadIdx.x & 63, wid = threadIdx.x >> 6;
  const int m0 = blockIdx.x * 64 + wid * 16;
  const int ar = lane & 15, ak = (lane >> 4) * 8;
  const int bb = m0 >> 11;  // m0/S_, block spans one b
  f32x4 acc = {};
  for (int k0 = 0; k0 < D_; k0 += 32) {
    bf16x8 a = *(const bf16x8*)&X[(size_t)(m0 + ar) * D_ + k0 + ak];
    if (SCALED) {
      const float* pp = pq + bb * D_ + k0 + ak;
      f32x4 p0 = *(const f32x4*)pp;
      f32x4 p1 = *(const f32x4*)(pp + 4);
      bf16x8 a2;
#pragma unroll
      for (int i = 0; i < 4; ++i) {
        a2[i]     = (bf16_t)((float)a[i] * p0[i]);
        a2[4 + i] = (bf16_t)((float)a[4 + i] * p1[i]);
      }
      a = a2;
    }
    bf16x8 b = *(const bf16x8*)&WaT[(size_t)ar * D_ + k0 + ak];
    acc = __builtin_amdgcn_mfma_f32_16x16x32_bf16(a, b, acc, 0, 0, 0);
  }
  const int h = lane & 15;
  const int srow = m0 + (lane >> 4) * 4;
  const int s0 = srow - bb * S_;
  const float bah = ba[h];
  f32x4 mv = *(const f32x4*)&mask[(size_t)bb * S_ + s0];
  f32x4 outv;
#pragma unroll
  for (int j = 0; j < 4; ++j)
    outv[j] = (acc[j] + bah) * SCALE + mv[j];
  *(f32x4*)&scores[((size_t)(bb * H_ + h)) * S_ + s0] = outv;
}

// ---------------------------------------------------------------------------
// softmax over each scores row -> normalized weights
// ---------------------------------------------------------------------------
__global__ __launch_bounds__(256)
void softmax_rows(const float* __restrict__ scores, float* __restrict__ wout) {
  __shared__ float rA[4], rB[4];
  const int tid = threadIdx.x, lane = tid & 63, wid = tid >> 6;
  const float* srow = scores + (size_t)blockIdx.x * S_;
  float* wrow = wout + (size_t)blockIdx.x * S_;
  f32x4 v0 = *(const f32x4*)&srow[tid * 4];
  f32x4 v1 = *(const f32x4*)&srow[1024 + tid * 4];
  float mx = fmaxf(fmaxf(fmaxf(v0[0], v0[1]), fmaxf(v0[2], v0[3])),
                   fmaxf(fmaxf(v1[0], v1[1]), fmaxf(v1[2], v1[3])));
#pragma unroll
  for (int o = 32; o; o >>= 1) mx = fmaxf(mx, __shfl_xor(mx, o));
  if (lane == 0) rA[wid] = mx;
  __syncthreads();
  mx = fmaxf(fmaxf(rA[0], rA[1]), fmaxf(rA[2], rA[3]));
  float sum = 0.f;
#pragma unroll
  for (int i = 0; i < 4; ++i) { v0[i] = __expf(v0[i] - mx); sum += v0[i]; }
#pragma unroll
  for (int i = 0; i < 4; ++i) { v1[i] = __expf(v1[i] - mx); sum += v1[i]; }
#pragma unroll
  for (int o = 32; o; o >>= 1) sum += __shfl_xor(sum, o);
  if (lane == 0) rB[wid] = sum;
  __syncthreads();
  sum = rB[0] + rB[1] + rB[2] + rB[3];
  const float inv = 1.0f / sum;
#pragma unroll
  for (int i = 0; i < 4; ++i) { v0[i] *= inv; v1[i] *= inv; }
  *(f32x4*)&wrow[tid * 4] = v0;
  *(f32x4*)&wrow[1024 + tid * 4] = v1;
}

// ---------------------------------------------------------------------------
// pool partials over 32-row chunks (coalesced bf16x8)
// ---------------------------------------------------------------------------
__global__ __launch_bounds__(256)
void pool_partial(const bf16_t* __restrict__ X, const float* __restrict__ w,
                  float* __restrict__ partials) {
  __shared__ float sm[2][1024];
  const int tid = threadIdx.x;
  const int chunk = blockIdx.x, b = blockIdx.y;
  const int s0 = chunk * 32;
  const int dc = (tid & 127) * 8;
  const int sp = tid >> 7;
  const int h = dc >> 6;
  const float* wrow = w + ((size_t)b * H_ + h) * S_ + s0;
  const bf16_t* Xb = X + ((size_t)b * S_ + s0) * D_ + dc;
  float acc[8] = {};
  for (int s = sp; s < 32; s += 2) {
    bf16x8 xv = *(const bf16x8*)&Xb[(size_t)s * D_];
    float wt = wrow[s];
#pragma unroll
    for (int j = 0; j < 8; ++j) acc[j] += wt * (float)xv[j];
  }
#pragma unroll
  for (int j = 0; j < 8; ++j) sm[sp][dc + j] = acc[j];
  __syncthreads();
  const int d0 = tid * 4;
  f32x4 r;
#pragma unroll
  for (int j = 0; j < 4; ++j) r[j] = sm[0][d0 + j] + sm[1][d0 + j];
  *(f32x4*)&partials[((size_t)chunk * B_ + b) * D_ + d0] = r;
}

// SCALED=1: pooled[b,d] = pq[b,d] * sum_c parts  (pk for deferred modulate)
template <int SCALED>
__global__ __launch_bounds__(256)
void pool_reduce(const float* __restrict__ partials, const float* __restrict__ pq,
                 float* __restrict__ pooled) {
  const int idx = blockIdx.x * 256 + threadIdx.x;
  float s = 0.f;
#pragma unroll 8
  for (int c = 0; c < 64; ++c) s += partials[(size_t)c * (B_ * D_) + idx];
  if (SCALED) s *= pq[idx];
  pooled[idx] = s;
}

// ---------------------------------------------------------------------------
extern "C" void kernel_launch(void* const* d_in, const int* in_sizes, int n_in,
                              void* d_out, int out_size, void* d_ws, size_t ws_size,
                              hipStream_t stream) {
  const float* hs   = (const float*)d_in[0];
  const float* mask = (const float*)d_in[1];
  const float* Wq   = (const float*)d_in[2];
  const float* bq   = (const float*)d_in[3];
  const float* Wqa  = (const float*)d_in[4];
  const float* bqa  = (const float*)d_in[5];
  const float* Wk   = (const float*)d_in[6];
  const float* bk   = (const float*)d_in[7];
  const float* Wka  = (const float*)d_in[8];
  const float* bka  = (const float*)d_in[9];
  const float* Wt   = (const float*)d_in[10];
  const float* bt   = (const float*)d_in[11];

  char* ws = (char*)d_ws;
  float*  pq    = (float*)(ws + (64u << 10));
  float*  pk    = (float*)(ws + (128u << 10));
  bf16_t* WqaT  = (bf16_t*)(ws + (1u << 20));
  bf16_t* WkaT  = (bf16_t*)(ws + (1u << 20) + 32768);
  bf16_t* WqT   = (bf16_t*)(ws + (2u << 20));
  bf16_t* WkT   = (bf16_t*)(ws + (4u << 20));
  bf16_t* WtT   = (bf16_t*)(ws + (6u << 20));
  bf16_t* hsb   = (bf16_t*)(ws + (8u << 20));
  bf16_t* mq    = (bf16_t*)(ws + (8u << 20) + ((size_t)64 << 20));
  bf16_t* mk    = (bf16_t*)(ws + (8u << 20) + ((size_t)128 << 20));
  float* scores = (float*)(ws + (8u << 20) + ((size_t)192 << 20));
  float* wsm    = (float*)(ws + (8u << 20) + ((size_t)194 << 20));
  float* parts  = (float*)(ws + (8u << 20) + ((size_t)196 << 20));

  // prep
  f32_to_bf16<<<16384, 256, 0, stream>>>(hs, hsb);
  transpose1024_all<<<dim3(16, 16, 3), 256, 0, stream>>>(Wq, Wk, Wt, WqT, WkT, WtT);
  transpose_small_all<<<8, 256, 0, stream>>>(Wqa, Wka, WqaT, WkaT);

  // mixed_q = hsb@Wq+bq AND mixed_k = hsb@Wk+bk in one dual-N launch
  gemm_qk<<<4096, 256, 0, stream>>>(hsb, WqT, WkT, bq, bk, mq, mk);

  // pooled_q from mixed_q
  score_kernel<0><<<512, 256, 0, stream>>>(mq, WqaT, bqa, mask, nullptr, scores);
  softmax_rows<<<256, 256, 0, stream>>>(scores, wsm);
  pool_partial<<<dim3(64, 16), 256, 0, stream>>>(mq, wsm, parts);
  pool_reduce<0><<<64, 256, 0, stream>>>(parts, nullptr, pq);

  // pooled_k from mixed_qk = mk*pq (applied on the fly; never materialized)
  score_kernel<1><<<512, 256, 0, stream>>>(mk, WkaT, bka, mask, pq, scores);
  softmax_rows<<<256, 256, 0, stream>>>(scores, wsm);
  pool_partial<<<dim3(64, 16), 256, 0, stream>>>(mk, wsm, parts);
  pool_reduce<1><<<64, 256, 0, stream>>>(parts, pq, pk);

  // out = (mq * pk) @ Wt + bt + mixed_q
  gemm_out<<<2048, 256, 0, stream>>>(mq, WtT, bt, (float*)d_out, mq, pk);
}

// Round 14
// 395.921 us; speedup vs baseline: 1.1142x; 1.0108x over previous
//
#include <hip/hip_runtime.h>
#include <hip/hip_bf16.h>
#include <stdint.h>

#define D_ 1024
#define H_ 16
#define DH_ 64
#define S_ 2048
#define B_ 16
static constexpr float SCALE = 0.125f;  // 1/sqrt(64)

typedef __bf16 bf16_t;
typedef __bf16 bf16x8 __attribute__((ext_vector_type(8)));
typedef __bf16 bf16x4 __attribute__((ext_vector_type(4)));
typedef float  f32x4  __attribute__((ext_vector_type(4)));

__device__ __forceinline__ void llds16(const void* g, void* l) {
  __builtin_amdgcn_global_load_lds(
      (const __attribute__((address_space(1))) void*)g,
      (__attribute__((address_space(3))) void*)l, 16, 0, 0);
}

// ---------------------------------------------------------------------------
// prep_all: one launch for all input preprocessing.
// z=0..2 : 1024x1024 f32->bf16 transpose (Wq,Wk,Wt)
// z=3    : [1024][16] -> [16][1024] small transposes (Wqa,Wka)
// z=4..19: hs f32 -> bf16 convert (16 slices)
// ---------------------------------------------------------------------------
__global__ __launch_bounds__(256)
void prep_all(const float* __restrict__ Wq, const float* __restrict__ Wk,
              const float* __restrict__ Wt, const float* __restrict__ Wqa,
              const float* __restrict__ Wka, const float* __restrict__ hs,
              bf16_t* __restrict__ WqT, bf16_t* __restrict__ WkT,
              bf16_t* __restrict__ WtT, bf16_t* __restrict__ WqaT,
              bf16_t* __restrict__ WkaT, bf16_t* __restrict__ hsb) {
  __shared__ bf16_t t[64][65];
  const int z = blockIdx.z;
  const int tid = threadIdx.x;
  if (z < 3) {
    const float* src = (z == 0) ? Wq : (z == 1) ? Wk : Wt;
    bf16_t* dst      = (z == 0) ? WqT : (z == 1) ? WkT : WtT;
    const int n0 = blockIdx.x * 64, k0 = blockIdx.y * 64;
    const int r = tid >> 4, c4 = (tid & 15) * 4;
#pragma unroll
    for (int p = 0; p < 4; ++p) {
      int row = p * 16 + r;
      f32x4 f = *(const f32x4*)&src[(size_t)(k0 + row) * 1024 + n0 + c4];
#pragma unroll
      for (int i = 0; i < 4; ++i) t[row][c4 + i] = (bf16_t)f[i];
    }
    __syncthreads();
#pragma unroll
    for (int p = 0; p < 4; ++p) {
      int row = p * 16 + r;
      bf16x4 v;
#pragma unroll
      for (int i = 0; i < 4; ++i) v[i] = t[c4 + i][row];
      *(bf16x4*)&dst[(size_t)(n0 + row) * 1024 + k0 + c4] = v;
    }
  } else if (z == 3) {
    int g = (blockIdx.y * 16 + blockIdx.x) * 256 + tid;
    if (g < 2048) {
      const float* src = (g < 1024) ? Wqa : Wka;
      bf16_t* dst      = (g < 1024) ? WqaT : WkaT;
      int k = g & 1023;
#pragma unroll
      for (int h = 0; h < H_; ++h) dst[h * 1024 + k] = (bf16_t)src[k * H_ + h];
    }
  } else {
    // hs convert: slice z-4 of 16; 256 blocks x 256 thr x 4 iters x 8 elems
    const int slice = z - 4;
    const int fb = blockIdx.y * 16 + blockIdx.x;
    const size_t tbase = ((size_t)slice * 256 + fb) * 256 + tid;
#pragma unroll
    for (int i = 0; i < 4; ++i) {
      size_t e = (tbase + (size_t)i * 1048576) * 8;
      f32x4 a = *(const f32x4*)&hs[e];
      f32x4 b = *(const f32x4*)&hs[e + 4];
      bf16x8 o;
#pragma unroll
      for (int j = 0; j < 4; ++j) { o[j] = (bf16_t)a[j]; o[4 + j] = (bf16_t)b[j]; }
      *(bf16x8*)&hsb[e] = o;
    }
  }
}

// ---------------------------------------------------------------------------
// Dual-N GEMM: mixed_q = hs@Wq+bq AND mixed_k = hs@Wk+bk in one launch.
// r11 inner loop (m97 128x128/BK=32, slot-rotation swizzle, staged epilogue).
// ---------------------------------------------------------------------------
__global__ __launch_bounds__(256, 2)
void gemm_qk(const bf16_t* __restrict__ A, const bf16_t* __restrict__ WqT,
             const bf16_t* __restrict__ WkT, const float* __restrict__ bq,
             const float* __restrict__ bk, bf16_t* __restrict__ mq,
             bf16_t* __restrict__ mk) {
  constexpr int K = 1024, N = 1024;
  __shared__ __align__(16) bf16_t lA[128 * 32];
  __shared__ __align__(16) bf16_t lB[128 * 32];
  __shared__ __align__(16) float est[4][16 * 68];
  const int tid = threadIdx.x;
  const int lane = tid & 63, wid = tid >> 6;
  const int wr = wid >> 1, wc = wid & 1;

  const int wgid = (blockIdx.x & 7) * 512 + (blockIdx.x >> 3);
  const int m0 = (wgid >> 4) * 128;
  const int nsel = wgid & 15;
  const int n0 = (nsel & 7) * 128;
  const bf16_t* BT = (nsel < 8) ? WqT : WkT;
  const float* bias = (nsel < 8) ? bq : bk;
  bf16_t* Cout = (nsel < 8) ? mq : mk;

  const int ar = lane & 15;
  const int kq = lane >> 4;

  int rowc[2], colc[2], dstoff[2];
#pragma unroll
  for (int j = 0; j < 2; ++j) {
    int c = j * 256 + tid;
    int row = c >> 2, s = c & 3;
    rowc[j] = row;
    colc[j] = (((s - (row >> 1)) & 3) << 3);
    dstoff[j] = c * 8;
  }

  f32x4 acc[4][4] = {};

  for (int k0 = 0; k0 < K; k0 += 32) {
#pragma unroll
    for (int j = 0; j < 2; ++j) {
      llds16(BT + (size_t)(n0 + rowc[j]) * K + k0 + colc[j], lB + dstoff[j]);
      llds16(A + (size_t)(m0 + rowc[j]) * K + k0 + colc[j], lA + dstoff[j]);
    }
    __syncthreads();
    bf16x8 af[4], bg[4];
#pragma unroll
    for (int m = 0; m < 4; ++m) {
      int r = wr * 64 + m * 16 + ar;
      af[m] = *(const bf16x8*)&lA[r * 32 + (((kq + (r >> 1)) & 3) << 3)];
    }
#pragma unroll
    for (int n = 0; n < 4; ++n) {
      int r = wc * 64 + n * 16 + ar;
      bg[n] = *(const bf16x8*)&lB[r * 32 + (((kq + (r >> 1)) & 3) << 3)];
    }
#pragma unroll
    for (int m = 0; m < 4; ++m)
#pragma unroll
      for (int n = 0; n < 4; ++n)
        acc[m][n] = __builtin_amdgcn_mfma_f32_16x16x32_bf16(af[m], bg[n], acc[m][n], 0, 0, 0);
    __syncthreads();
  }

  float* st = est[wid];
  const int erow = lane >> 2;
  const int ecol = (lane & 3) * 16;
  const int gcb = n0 + wc * 64;
  const int qrow = (lane >> 4) * 4;
  const int qcol = lane & 15;
  f32x4 bb[4];
#pragma unroll
  for (int q = 0; q < 4; ++q) bb[q] = *(const f32x4*)&bias[gcb + ecol + q * 4];
#pragma unroll
  for (int m = 0; m < 4; ++m) {
#pragma unroll
    for (int n = 0; n < 4; ++n)
#pragma unroll
      for (int j = 0; j < 4; ++j)
        st[(qrow + j) * 68 + n * 16 + qcol] = acc[m][n][j];
    asm volatile("s_waitcnt lgkmcnt(0)" ::: "memory");
    __builtin_amdgcn_sched_barrier(0);
    const int grow = m0 + wr * 64 + m * 16 + erow;
    f32x4 v[4];
#pragma unroll
    for (int q = 0; q < 4; ++q) v[q] = *(f32x4*)&st[erow * 68 + ecol + q * 4];
#pragma unroll
    for (int q = 0; q < 4; ++q)
#pragma unroll
      for (int i = 0; i < 4; ++i) v[q][i] += bb[q][i];
    bf16x8 o0, o1;
#pragma unroll
    for (int i = 0; i < 4; ++i) { o0[i] = (bf16_t)v[0][i]; o0[4 + i] = (bf16_t)v[1][i]; }
#pragma unroll
    for (int i = 0; i < 4; ++i) { o1[i] = (bf16_t)v[2][i]; o1[4 + i] = (bf16_t)v[3][i]; }
    bf16_t* op = Cout + (size_t)grow * N + gcb + ecol;
    *(bf16x8*)&op[0] = o0;
    *(bf16x8*)&op[8] = o1;
  }
}

// ---------------------------------------------------------------------------
// Final GEMM: out = (mq * pkA) @ WtT + bt + resid(mq)  -> f32
// ---------------------------------------------------------------------------
__global__ __launch_bounds__(256, 2)
void gemm_out(const bf16_t* __restrict__ A, const bf16_t* __restrict__ BT,
              const float* __restrict__ bias, float* __restrict__ Cout,
              const bf16_t* __restrict__ resid, const float* __restrict__ pkA) {
  constexpr int K = 1024, N = 1024;
  __shared__ __align__(16) bf16_t lA[128 * 32];
  __shared__ __align__(16) bf16_t lB[128 * 32];
  __shared__ __align__(16) float est[4][16 * 68];
  const int tid = threadIdx.x;
  const int lane = tid & 63, wid = tid >> 6;
  const int wr = wid >> 1, wc = wid & 1;

  const int wgid = (blockIdx.x & 7) * 256 + (blockIdx.x >> 3);
  const int m0 = (wgid >> 3) * 128;
  const int n0 = (wgid & 7) * 128;
  const int b = m0 / S_;

  const int ar = lane & 15;
  const int kq = lane >> 4;

  int rowc[2], colc[2], dstoff[2];
#pragma unroll
  for (int j = 0; j < 2; ++j) {
    int c = j * 256 + tid;
    int row = c >> 2, s = c & 3;
    rowc[j] = row;
    colc[j] = (((s - (row >> 1)) & 3) << 3);
    dstoff[j] = c * 8;
  }

  f32x4 acc[4][4] = {};

  for (int k0 = 0; k0 < K; k0 += 32) {
#pragma unroll
    for (int j = 0; j < 2; ++j) {
      llds16(BT + (size_t)(n0 + rowc[j]) * K + k0 + colc[j], lB + dstoff[j]);
      bf16x8 v = *(const bf16x8*)(A + (size_t)(m0 + rowc[j]) * K + k0 + colc[j]);
      const float* pkp = pkA + b * D_ + k0 + colc[j];
      f32x4 p0 = *(const f32x4*)pkp;
      f32x4 p1 = *(const f32x4*)(pkp + 4);
      bf16x8 o;
#pragma unroll
      for (int i = 0; i < 4; ++i) {
        o[i]     = (bf16_t)((float)v[i] * p0[i]);
        o[4 + i] = (bf16_t)((float)v[4 + i] * p1[i]);
      }
      *(bf16x8*)&lA[dstoff[j]] = o;
    }
    __syncthreads();
    bf16x8 af[4], bg[4];
#pragma unroll
    for (int m = 0; m < 4; ++m) {
      int r = wr * 64 + m * 16 + ar;
      af[m] = *(const bf16x8*)&lA[r * 32 + (((kq + (r >> 1)) & 3) << 3)];
    }
#pragma unroll
    for (int n = 0; n < 4; ++n) {
      int r = wc * 64 + n * 16 + ar;
      bg[n] = *(const bf16x8*)&lB[r * 32 + (((kq + (r >> 1)) & 3) << 3)];
    }
#pragma unroll
    for (int m = 0; m < 4; ++m)
#pragma unroll
      for (int n = 0; n < 4; ++n)
        acc[m][n] = __builtin_amdgcn_mfma_f32_16x16x32_bf16(af[m], bg[n], acc[m][n], 0, 0, 0);
    __syncthreads();
  }

  float* st = est[wid];
  const int erow = lane >> 2;
  const int ecol = (lane & 3) * 16;
  const int gcb = n0 + wc * 64;
  const int qrow = (lane >> 4) * 4;
  const int qcol = lane & 15;
  f32x4 bb[4];
#pragma unroll
  for (int q = 0; q < 4; ++q) bb[q] = *(const f32x4*)&bias[gcb + ecol + q * 4];
#pragma unroll
  for (int m = 0; m < 4; ++m) {
#pragma unroll
    for (int n = 0; n < 4; ++n)
#pragma unroll
      for (int j = 0; j < 4; ++j)
        st[(qrow + j) * 68 + n * 16 + qcol] = acc[m][n][j];
    asm volatile("s_waitcnt lgkmcnt(0)" ::: "memory");
    __builtin_amdgcn_sched_barrier(0);
    const int grow = m0 + wr * 64 + m * 16 + erow;
    f32x4 v[4];
#pragma unroll
    for (int q = 0; q < 4; ++q) v[q] = *(f32x4*)&st[erow * 68 + ecol + q * 4];
#pragma unroll
    for (int q = 0; q < 4; ++q)
#pragma unroll
      for (int i = 0; i < 4; ++i) v[q][i] += bb[q][i];
    bf16x8 r0 = *(const bf16x8*)&resid[(size_t)grow * N + gcb + ecol];
    bf16x8 r1 = *(const bf16x8*)&resid[(size_t)grow * N + gcb + ecol + 8];
#pragma unroll
    for (int i = 0; i < 4; ++i) { v[0][i] += (float)r0[i]; v[1][i] += (float)r0[4 + i]; }
#pragma unroll
    for (int i = 0; i < 4; ++i) { v[2][i] += (float)r1[i]; v[3][i] += (float)r1[4 + i]; }
    float* op = Cout + (size_t)grow * N + gcb + ecol;
#pragma unroll
    for (int q = 0; q < 4; ++q) *(f32x4*)&op[q * 4] = v[q];
  }
}

// ---------------------------------------------------------------------------
// scores[b*H+h][s] = (X[b,s,:] . Wa[h,:] + ba[h]) * SCALE + mask[b][s]
// PER_B=1: Wa is per-batch (pre-scaled wka_s[b]) -> identical loop cost to
// PER_B=0 (the pq multiply was folded into B at pool_reduce<0>).
// ---------------------------------------------------------------------------
template <int PER_B>
__global__ __launch_bounds__(256)
void score_kernel(const bf16_t* __restrict__ X, const bf16_t* __restrict__ WaT,
                  const float* __restrict__ ba, const float* __restrict__ mask,
                  float* __restrict__ scores) {
  const int lane = threadIdx.x & 63, wid = threadIdx.x >> 6;
  const int m0 = blockIdx.x * 64 + wid * 16;
  const int ar = lane & 15, ak = (lane >> 4) * 8;
  const int bb = m0 >> 11;
  const bf16_t* Wb = WaT + (PER_B ? (size_t)bb * H_ * D_ : 0);
  f32x4 acc = {};
  for (int k0 = 0; k0 < D_; k0 += 32) {
    bf16x8 a = *(const bf16x8*)&X[(size_t)(m0 + ar) * D_ + k0 + ak];
    bf16x8 b = *(const bf16x8*)&Wb[(size_t)ar * D_ + k0 + ak];
    acc = __builtin_amdgcn_mfma_f32_16x16x32_bf16(a, b, acc, 0, 0, 0);
  }
  const int h = lane & 15;
  const int srow = m0 + (lane >> 4) * 4;
  const int s0 = srow - bb * S_;
  const float bah = ba[h];
  f32x4 mv = *(const f32x4*)&mask[(size_t)bb * S_ + s0];
  f32x4 outv;
#pragma unroll
  for (int j = 0; j < 4; ++j)
    outv[j] = (acc[j] + bah) * SCALE + mv[j];
  *(f32x4*)&scores[((size_t)(bb * H_ + h)) * S_ + s0] = outv;
}

// ---------------------------------------------------------------------------
// softmax over each scores row -> normalized weights
// ---------------------------------------------------------------------------
__global__ __launch_bounds__(256)
void softmax_rows(const float* __restrict__ scores, float* __restrict__ wout) {
  __shared__ float rA[4], rB[4];
  const int tid = threadIdx.x, lane = tid & 63, wid = tid >> 6;
  const float* srow = scores + (size_t)blockIdx.x * S_;
  float* wrow = wout + (size_t)blockIdx.x * S_;
  f32x4 v0 = *(const f32x4*)&srow[tid * 4];
  f32x4 v1 = *(const f32x4*)&srow[1024 + tid * 4];
  float mx = fmaxf(fmaxf(fmaxf(v0[0], v0[1]), fmaxf(v0[2], v0[3])),
                   fmaxf(fmaxf(v1[0], v1[1]), fmaxf(v1[2], v1[3])));
#pragma unroll
  for (int o = 32; o; o >>= 1) mx = fmaxf(mx, __shfl_xor(mx, o));
  if (lane == 0) rA[wid] = mx;
  __syncthreads();
  mx = fmaxf(fmaxf(rA[0], rA[1]), fmaxf(rA[2], rA[3]));
  float sum = 0.f;
#pragma unroll
  for (int i = 0; i < 4; ++i) { v0[i] = __expf(v0[i] - mx); sum += v0[i]; }
#pragma unroll
  for (int i = 0; i < 4; ++i) { v1[i] = __expf(v1[i] - mx); sum += v1[i]; }
#pragma unroll
  for (int o = 32; o; o >>= 1) sum += __shfl_xor(sum, o);
  if (lane == 0) rB[wid] = sum;
  __syncthreads();
  sum = rB[0] + rB[1] + rB[2] + rB[3];
  const float inv = 1.0f / sum;
#pragma unroll
  for (int i = 0; i < 4; ++i) { v0[i] *= inv; v1[i] *= inv; }
  *(f32x4*)&wrow[tid * 4] = v0;
  *(f32x4*)&wrow[1024 + tid * 4] = v1;
}

// ---------------------------------------------------------------------------
// pool partials over 32-row chunks (coalesced bf16x8)
// ---------------------------------------------------------------------------
__global__ __launch_bounds__(256)
void pool_partial(const bf16_t* __restrict__ X, const float* __restrict__ w,
                  float* __restrict__ partials) {
  __shared__ float sm[2][1024];
  const int tid = threadIdx.x;
  const int chunk = blockIdx.x, b = blockIdx.y;
  const int s0 = chunk * 32;
  const int dc = (tid & 127) * 8;
  const int sp = tid >> 7;
  const int h = dc >> 6;
  const float* wrow = w + ((size_t)b * H_ + h) * S_ + s0;
  const bf16_t* Xb = X + ((size_t)b * S_ + s0) * D_ + dc;
  float acc[8] = {};
  for (int s = sp; s < 32; s += 2) {
    bf16x8 xv = *(const bf16x8*)&Xb[(size_t)s * D_];
    float wt = wrow[s];
#pragma unroll
    for (int j = 0; j < 8; ++j) acc[j] += wt * (float)xv[j];
  }
#pragma unroll
  for (int j = 0; j < 8; ++j) sm[sp][dc + j] = acc[j];
  __syncthreads();
  const int d0 = tid * 4;
  f32x4 r;
#pragma unroll
  for (int j = 0; j < 4; ++j) r[j] = sm[0][d0 + j] + sm[1][d0 + j];
  *(f32x4*)&partials[((size_t)chunk * B_ + b) * D_ + d0] = r;
}

// MODE 0: pq[idx] = sum; ALSO write wka_s[b][h][d] = bf16(pq * Wka[h][d])
// MODE 1: pk[idx] = sum * pq[idx]   (deferred mixed_qk modulate)
template <int MODE>
__global__ __launch_bounds__(256)
void pool_reduce(const float* __restrict__ partials, const float* __restrict__ pq,
                 const bf16_t* __restrict__ WkaT, float* __restrict__ pooled,
                 bf16_t* __restrict__ wka_s) {
  const int idx = blockIdx.x * 256 + threadIdx.x;  // b*D + d
  float s = 0.f;
#pragma unroll 8
  for (int c = 0; c < 64; ++c) s += partials[(size_t)c * (B_ * D_) + idx];
  if (MODE == 1) s *= pq[idx];
  pooled[idx] = s;
  if (MODE == 0) {
    const int b = idx >> 10, d = idx & 1023;
#pragma unroll
    for (int h = 0; h < H_; ++h)
      wka_s[((size_t)b * H_ + h) * D_ + d] = (bf16_t)(s * (float)WkaT[h * D_ + d]);
  }
}

// ---------------------------------------------------------------------------
extern "C" void kernel_launch(void* const* d_in, const int* in_sizes, int n_in,
                              void* d_out, int out_size, void* d_ws, size_t ws_size,
                              hipStream_t stream) {
  const float* hs   = (const float*)d_in[0];
  const float* mask = (const float*)d_in[1];
  const float* Wq   = (const float*)d_in[2];
  const float* bq   = (const float*)d_in[3];
  const float* Wqa  = (const float*)d_in[4];
  const float* bqa  = (const float*)d_in[5];
  const float* Wk   = (const float*)d_in[6];
  const float* bk   = (const float*)d_in[7];
  const float* Wka  = (const float*)d_in[8];
  const float* bka  = (const float*)d_in[9];
  const float* Wt   = (const float*)d_in[10];
  const float* bt   = (const float*)d_in[11];

  char* ws = (char*)d_ws;
  float*  pq    = (float*)(ws + (64u << 10));
  float*  pk    = (float*)(ws + (128u << 10));
  bf16_t* wka_s = (bf16_t*)(ws + (256u << 10));                  // 512 KB
  bf16_t* WqaT  = (bf16_t*)(ws + (1u << 20));
  bf16_t* WkaT  = (bf16_t*)(ws + (1u << 20) + 32768);
  bf16_t* WqT   = (bf16_t*)(ws + (2u << 20));
  bf16_t* WkT   = (bf16_t*)(ws + (4u << 20));
  bf16_t* WtT   = (bf16_t*)(ws + (6u << 20));
  bf16_t* hsb   = (bf16_t*)(ws + (8u << 20));
  bf16_t* mq    = (bf16_t*)(ws + (8u << 20) + ((size_t)64 << 20));
  bf16_t* mk    = (bf16_t*)(ws + (8u << 20) + ((size_t)128 << 20));
  float* scores = (float*)(ws + (8u << 20) + ((size_t)192 << 20));
  float* wsm    = (float*)(ws + (8u << 20) + ((size_t)194 << 20));
  float* parts  = (float*)(ws + (8u << 20) + ((size_t)196 << 20));

  // all prep in one launch
  prep_all<<<dim3(16, 16, 20), 256, 0, stream>>>(Wq, Wk, Wt, Wqa, Wka, hs,
                                                 WqT, WkT, WtT, WqaT, WkaT, hsb);

  // mixed_q and mixed_k in one dual-N launch
  gemm_qk<<<4096, 256, 0, stream>>>(hsb, WqT, WkT, bq, bk, mq, mk);

  // pooled_q from mixed_q; pool_reduce<0> also emits wka_s = pq (.) Wka
  score_kernel<0><<<512, 256, 0, stream>>>(mq, WqaT, bqa, mask, scores);
  softmax_rows<<<256, 256, 0, stream>>>(scores, wsm);
  pool_partial<<<dim3(64, 16), 256, 0, stream>>>(mq, wsm, parts);
  pool_reduce<0><<<64, 256, 0, stream>>>(parts, nullptr, WkaT, pq, wka_s);

  // pooled_k: score2 uses pre-scaled per-b B (wka_s) -> same cost as score<0>
  score_kernel<1><<<512, 256, 0, stream>>>(mk, wka_s, bka, mask, scores);
  softmax_rows<<<256, 256, 0, stream>>>(scores, wsm);
  pool_partial<<<dim3(64, 16), 256, 0, stream>>>(mk, wsm, parts);
  pool_reduce<1><<<64, 256, 0, stream>>>(parts, pq, nullptr, pk, nullptr);

  // out = (mq * pk) @ Wt + bt + mixed_q
  gemm_out<<<2048, 256, 0, stream>>>(mq, WtT, bt, (float*)d_out, mq, pk);
}

// Round 15
// 365.442 us; speedup vs baseline: 1.2072x; 1.0834x over previous
//
#include <hip/hip_runtime.h>
#include <hip/hip_bf16.h>
#include <stdint.h>

#define D_ 1024
#define H_ 16
#define DH_ 64
#define S_ 2048
#define B_ 16
static constexpr float SCALE = 0.125f;  // 1/sqrt(64)

typedef __bf16 bf16_t;
typedef __bf16 bf16x8 __attribute__((ext_vector_type(8)));
typedef __bf16 bf16x4 __attribute__((ext_vector_type(4)));
typedef float  f32x4  __attribute__((ext_vector_type(4)));

__device__ __forceinline__ void llds16(const void* g, void* l) {
  __builtin_amdgcn_global_load_lds(
      (const __attribute__((address_space(1))) void*)g,
      (__attribute__((address_space(3))) void*)l, 16, 0, 0);
}

// ---------------------------------------------------------------------------
// prep_all: one launch for all input preprocessing.
// z=0..2 : 1024x1024 f32->bf16 transpose (Wq,Wk,Wt)
// z=3    : [1024][16] -> [16][1024] small transposes (Wqa,Wka)
// z=4..19: hs f32 -> bf16 convert (16 slices)
// ---------------------------------------------------------------------------
__global__ __launch_bounds__(256)
void prep_all(const float* __restrict__ Wq, const float* __restrict__ Wk,
              const float* __restrict__ Wt, const float* __restrict__ Wqa,
              const float* __restrict__ Wka, const float* __restrict__ hs,
              bf16_t* __restrict__ WqT, bf16_t* __restrict__ WkT,
              bf16_t* __restrict__ WtT, bf16_t* __restrict__ WqaT,
              bf16_t* __restrict__ WkaT, bf16_t* __restrict__ hsb) {
  __shared__ bf16_t t[64][65];
  const int z = blockIdx.z;
  const int tid = threadIdx.x;
  if (z < 3) {
    const float* src = (z == 0) ? Wq : (z == 1) ? Wk : Wt;
    bf16_t* dst      = (z == 0) ? WqT : (z == 1) ? WkT : WtT;
    const int n0 = blockIdx.x * 64, k0 = blockIdx.y * 64;
    const int r = tid >> 4, c4 = (tid & 15) * 4;
#pragma unroll
    for (int p = 0; p < 4; ++p) {
      int row = p * 16 + r;
      f32x4 f = *(const f32x4*)&src[(size_t)(k0 + row) * 1024 + n0 + c4];
#pragma unroll
      for (int i = 0; i < 4; ++i) t[row][c4 + i] = (bf16_t)f[i];
    }
    __syncthreads();
#pragma unroll
    for (int p = 0; p < 4; ++p) {
      int row = p * 16 + r;
      bf16x4 v;
#pragma unroll
      for (int i = 0; i < 4; ++i) v[i] = t[c4 + i][row];
      *(bf16x4*)&dst[(size_t)(n0 + row) * 1024 + k0 + c4] = v;
    }
  } else if (z == 3) {
    int g = (blockIdx.y * 16 + blockIdx.x) * 256 + tid;
    if (g < 2048) {
      const float* src = (g < 1024) ? Wqa : Wka;
      bf16_t* dst      = (g < 1024) ? WqaT : WkaT;
      int k = g & 1023;
#pragma unroll
      for (int h = 0; h < H_; ++h) dst[h * 1024 + k] = (bf16_t)src[k * H_ + h];
    }
  } else {
    const int slice = z - 4;
    const int fb = blockIdx.y * 16 + blockIdx.x;
    const size_t tbase = ((size_t)slice * 256 + fb) * 256 + tid;
#pragma unroll
    for (int i = 0; i < 4; ++i) {
      size_t e = (tbase + (size_t)i * 1048576) * 8;
      f32x4 a = *(const f32x4*)&hs[e];
      f32x4 b = *(const f32x4*)&hs[e + 4];
      bf16x8 o;
#pragma unroll
      for (int j = 0; j < 4; ++j) { o[j] = (bf16_t)a[j]; o[4 + j] = (bf16_t)b[j]; }
      *(bf16x8*)&hsb[e] = o;
    }
  }
}

// ---------------------------------------------------------------------------
// Dual-N 256x256 8-phase GEMM: mixed_q = hs@Wq+bq AND mixed_k = hs@Wk+bk.
// BK=64 split into 2 k-halves; LDS regions [dbuf][A|B][kh] (16KB each,
// 128KB total). Per K-tile: 4 phases (kh,mh), each {stage 1 half-tile of
// tile t+1 into the OTHER dbuf; [vmcnt(6)+barrier at ph1/ph3]; 8 ds_read;
// setprio 16-MFMA}. vmcnt(6) = 3 half-tiles in flight (counted, never 0
// until the peeled last tile). Slot-rotation swizzle (involution, 0-confl).
// Liveness: kh0 regions read only ph1-2, kh1 only ph3-4; cross-buffer
// stages protected by the ph1/ph3 barriers (all prior reads complete).
// ---------------------------------------------------------------------------
__global__ __launch_bounds__(512, 1)
void gemm_qk(const bf16_t* __restrict__ A, const bf16_t* __restrict__ WqT,
             const bf16_t* __restrict__ WkT, const float* __restrict__ bq,
             const float* __restrict__ bk, bf16_t* __restrict__ mq,
             bf16_t* __restrict__ mk) {
  constexpr int K = 1024, N = 1024;
  // [dbuf][mat A=0/B=1][kh][256 rows x 32 k]
  __shared__ __align__(16) bf16_t lds[2][2][2][256 * 32];
  const int tid = threadIdx.x;
  const int lane = tid & 63, wid = tid >> 6;   // 8 waves
  const int wm = wid >> 2, wn = wid & 3;       // 2 x 4 wave grid

  // XCD swizzle: nwg=1024, 1024%8==0 -> 128 contiguous ids per XCD
  const int wgid = (blockIdx.x & 7) * 128 + (blockIdx.x >> 3);
  const int m0 = (wgid >> 3) * 256;
  const int nsel = wgid & 7;                   // 0..3 Wq, 4..7 Wk
  const int n0 = (nsel & 3) * 256;
  const bf16_t* BT = (nsel < 4) ? WqT : WkT;
  const float* bias = (nsel < 4) ? bq : bk;
  bf16_t* Cout = (nsel < 4) ? mq : mk;

  // staging map: per half-tile (256 rows x 32 k = 16KB), 2 chunks/thread.
  // chunk c: row=c>>2, slot=c&3; slot s of row r holds global k-chunk
  // (s-(r&3))&3 (involution rotation; linear llds16 dest = c*16B).
  int srow[2], scol[2];
#pragma unroll
  for (int ld = 0; ld < 2; ++ld) {
    int c = ld * 512 + tid;
    srow[ld] = c >> 2;
    scol[ld] = (((c & 3) - (srow[ld] & 3)) & 3) * 8;
  }

  const int ar = lane & 15;
  const int kc = lane >> 4;  // k-chunk 0..3 within a 32-k half

  f32x4 acc[8][4] = {};

#define STAGE_(MAT, KH, KOFF, NXT)                                             \
  {                                                                            \
    const bf16_t* srcb = (MAT == 0) ? A : BT;                                  \
    const int rb = (MAT == 0) ? m0 : n0;                                       \
    _Pragma("unroll")                                                          \
    for (int ld = 0; ld < 2; ++ld) {                                           \
      llds16(srcb + (size_t)(rb + srow[ld]) * K + (KOFF) + (KH) * 32 + scol[ld], \
             &lds[NXT][MAT][KH][(ld * 512 + tid) * 8]);                        \
    }                                                                          \
  }

#define COMPUTE_(KH, MH, CUR)                                                  \
  {                                                                            \
    bf16x8 af[4], bg[4];                                                       \
    _Pragma("unroll")                                                          \
    for (int mm = 0; mm < 4; ++mm) {                                           \
      int r = wm * 128 + ((MH) * 4 + mm) * 16 + ar;                            \
      int slot = (kc + (r & 3)) & 3;                                           \
      af[mm] = *(const bf16x8*)&lds[CUR][0][KH][r * 32 + slot * 8];            \
    }                                                                          \
    _Pragma("unroll")                                                          \
    for (int nn = 0; nn < 4; ++nn) {                                           \
      int r = wn * 64 + nn * 16 + ar;                                          \
      int slot = (kc + (r & 3)) & 3;                                           \
      bg[nn] = *(const bf16x8*)&lds[CUR][1][KH][r * 32 + slot * 8];            \
    }                                                                          \
    __builtin_amdgcn_s_setprio(1);                                             \
    _Pragma("unroll")                                                          \
    for (int mm = 0; mm < 4; ++mm)                                             \
      _Pragma("unroll")                                                        \
      for (int nn = 0; nn < 4; ++nn)                                           \
        acc[(MH) * 4 + mm][nn] = __builtin_amdgcn_mfma_f32_16x16x32_bf16(      \
            af[mm], bg[nn], acc[(MH) * 4 + mm][nn], 0, 0, 0);                  \
    __builtin_amdgcn_s_setprio(0);                                             \
  }

  // prologue: stage tile 0 (order A-kh0, B-kh0, A-kh1, B-kh1)
  STAGE_(0, 0, 0, 0); STAGE_(1, 0, 0, 0); STAGE_(0, 1, 0, 0); STAGE_(1, 1, 0, 0);

#pragma unroll 1
  for (int t = 0; t < 15; ++t) {
    const int cur = t & 1, nxt = cur ^ 1;
    const int koff = (t + 1) * 64;
    // ph1
    STAGE_(0, 0, koff, nxt);
    asm volatile("s_waitcnt vmcnt(6)" ::: "memory");
    __builtin_amdgcn_s_barrier();
    COMPUTE_(0, 0, cur);
    // ph2
    STAGE_(1, 0, koff, nxt);
    COMPUTE_(0, 1, cur);
    // ph3
    STAGE_(0, 1, koff, nxt);
    asm volatile("s_waitcnt vmcnt(6)" ::: "memory");
    __builtin_amdgcn_s_barrier();
    COMPUTE_(1, 0, cur);
    // ph4
    STAGE_(1, 1, koff, nxt);
    COMPUTE_(1, 1, cur);
  }
  // peeled last tile (t=15, cur=1): no staging
  asm volatile("s_waitcnt vmcnt(4)" ::: "memory");
  __builtin_amdgcn_s_barrier();
  COMPUTE_(0, 0, 1);
  COMPUTE_(0, 1, 1);
  asm volatile("s_waitcnt vmcnt(0)" ::: "memory");
  __builtin_amdgcn_s_barrier();
  COMPUTE_(1, 0, 1);
  COMPUTE_(1, 1, 1);
#undef STAGE_
#undef COMPUTE_

  __syncthreads();  // all tile reads done before est overlay

  // ----- epilogue: LDS-staged coalesced stores (refcheck'd r5-r14) -----
  float* st = (float*)&lds[0][0][0][0] + wid * (16 * 68);
  const int erow = lane >> 2;          // 0..15
  const int ecol = (lane & 3) * 16;    // 0,16,32,48
  const int gcb = n0 + wn * 64;        // wave col base
  const int qrow = (lane >> 4) * 4;
  const int qcol = lane & 15;
  f32x4 bb[4];
#pragma unroll
  for (int q = 0; q < 4; ++q) bb[q] = *(const f32x4*)&bias[gcb + ecol + q * 4];
#pragma unroll
  for (int m = 0; m < 8; ++m) {
#pragma unroll
    for (int n = 0; n < 4; ++n)
#pragma unroll
      for (int j = 0; j < 4; ++j)
        st[(qrow + j) * 68 + n * 16 + qcol] = acc[m][n][j];
    asm volatile("s_waitcnt lgkmcnt(0)" ::: "memory");
    __builtin_amdgcn_sched_barrier(0);
    const int grow = m0 + wm * 128 + m * 16 + erow;
    f32x4 v[4];
#pragma unroll
    for (int q = 0; q < 4; ++q) v[q] = *(f32x4*)&st[erow * 68 + ecol + q * 4];
#pragma unroll
    for (int q = 0; q < 4; ++q)
#pragma unroll
      for (int i = 0; i < 4; ++i) v[q][i] += bb[q][i];
    bf16x8 o0, o1;
#pragma unroll
    for (int i = 0; i < 4; ++i) { o0[i] = (bf16_t)v[0][i]; o0[4 + i] = (bf16_t)v[1][i]; }
#pragma unroll
    for (int i = 0; i < 4; ++i) { o1[i] = (bf16_t)v[2][i]; o1[4 + i] = (bf16_t)v[3][i]; }
    bf16_t* op = Cout + (size_t)grow * N + gcb + ecol;
    *(bf16x8*)&op[0] = o0;
    *(bf16x8*)&op[8] = o1;
  }
}

// ---------------------------------------------------------------------------
// Final GEMM: out = (mq * pkA) @ WtT + bt + resid(mq)  -> f32  (r14 version)
// ---------------------------------------------------------------------------
__global__ __launch_bounds__(256, 2)
void gemm_out(const bf16_t* __restrict__ A, const bf16_t* __restrict__ BT,
              const float* __restrict__ bias, float* __restrict__ Cout,
              const bf16_t* __restrict__ resid, const float* __restrict__ pkA) {
  constexpr int K = 1024, N = 1024;
  __shared__ __align__(16) bf16_t lA[128 * 32];
  __shared__ __align__(16) bf16_t lB[128 * 32];
  __shared__ __align__(16) float est[4][16 * 68];
  const int tid = threadIdx.x;
  const int lane = tid & 63, wid = tid >> 6;
  const int wr = wid >> 1, wc = wid & 1;

  const int wgid = (blockIdx.x & 7) * 256 + (blockIdx.x >> 3);
  const int m0 = (wgid >> 3) * 128;
  const int n0 = (wgid & 7) * 128;
  const int b = m0 / S_;

  const int ar = lane & 15;
  const int kq = lane >> 4;

  int rowc[2], colc[2], dstoff[2];
#pragma unroll
  for (int j = 0; j < 2; ++j) {
    int c = j * 256 + tid;
    int row = c >> 2, s = c & 3;
    rowc[j] = row;
    colc[j] = (((s - (row >> 1)) & 3) << 3);
    dstoff[j] = c * 8;
  }

  f32x4 acc[4][4] = {};

  for (int k0 = 0; k0 < K; k0 += 32) {
#pragma unroll
    for (int j = 0; j < 2; ++j) {
      llds16(BT + (size_t)(n0 + rowc[j]) * K + k0 + colc[j], lB + dstoff[j]);
      bf16x8 v = *(const bf16x8*)(A + (size_t)(m0 + rowc[j]) * K + k0 + colc[j]);
      const float* pkp = pkA + b * D_ + k0 + colc[j];
      f32x4 p0 = *(const f32x4*)pkp;
      f32x4 p1 = *(const f32x4*)(pkp + 4);
      bf16x8 o;
#pragma unroll
      for (int i = 0; i < 4; ++i) {
        o[i]     = (bf16_t)((float)v[i] * p0[i]);
        o[4 + i] = (bf16_t)((float)v[4 + i] * p1[i]);
      }
      *(bf16x8*)&lA[dstoff[j]] = o;
    }
    __syncthreads();
    bf16x8 af[4], bg[4];
#pragma unroll
    for (int m = 0; m < 4; ++m) {
      int r = wr * 64 + m * 16 + ar;
      af[m] = *(const bf16x8*)&lA[r * 32 + (((kq + (r >> 1)) & 3) << 3)];
    }
#pragma unroll
    for (int n = 0; n < 4; ++n) {
      int r = wc * 64 + n * 16 + ar;
      bg[n] = *(const bf16x8*)&lB[r * 32 + (((kq + (r >> 1)) & 3) << 3)];
    }
#pragma unroll
    for (int m = 0; m < 4; ++m)
#pragma unroll
      for (int n = 0; n < 4; ++n)
        acc[m][n] = __builtin_amdgcn_mfma_f32_16x16x32_bf16(af[m], bg[n], acc[m][n], 0, 0, 0);
    __syncthreads();
  }

  float* st = est[wid];
  const int erow = lane >> 2;
  const int ecol = (lane & 3) * 16;
  const int gcb = n0 + wc * 64;
  const int qrow = (lane >> 4) * 4;
  const int qcol = lane & 15;
  f32x4 bb[4];
#pragma unroll
  for (int q = 0; q < 4; ++q) bb[q] = *(const f32x4*)&bias[gcb + ecol + q * 4];
#pragma unroll
  for (int m = 0; m < 4; ++m) {
#pragma unroll
    for (int n = 0; n < 4; ++n)
#pragma unroll
      for (int j = 0; j < 4; ++j)
        st[(qrow + j) * 68 + n * 16 + qcol] = acc[m][n][j];
    asm volatile("s_waitcnt lgkmcnt(0)" ::: "memory");
    __builtin_amdgcn_sched_barrier(0);
    const int grow = m0 + wr * 64 + m * 16 + erow;
    f32x4 v[4];
#pragma unroll
    for (int q = 0; q < 4; ++q) v[q] = *(f32x4*)&st[erow * 68 + ecol + q * 4];
#pragma unroll
    for (int q = 0; q < 4; ++q)
#pragma unroll
      for (int i = 0; i < 4; ++i) v[q][i] += bb[q][i];
    bf16x8 r0 = *(const bf16x8*)&resid[(size_t)grow * N + gcb + ecol];
    bf16x8 r1 = *(const bf16x8*)&resid[(size_t)grow * N + gcb + ecol + 8];
#pragma unroll
    for (int i = 0; i < 4; ++i) { v[0][i] += (float)r0[i]; v[1][i] += (float)r0[4 + i]; }
#pragma unroll
    for (int i = 0; i < 4; ++i) { v[2][i] += (float)r1[i]; v[3][i] += (float)r1[4 + i]; }
    float* op = Cout + (size_t)grow * N + gcb + ecol;
#pragma unroll
    for (int q = 0; q < 4; ++q) *(f32x4*)&op[q * 4] = v[q];
  }
}

// ---------------------------------------------------------------------------
// scores[b*H+h][s] = (X[b,s,:] . Wa[h,:] + ba[h]) * SCALE + mask[b][s]
// PER_B=1: Wa is per-batch (pre-scaled wka_s[b]).
// ---------------------------------------------------------------------------
template <int PER_B>
__global__ __launch_bounds__(256)
void score_kernel(const bf16_t* __restrict__ X, const bf16_t* __restrict__ WaT,
                  const float* __restrict__ ba, const float* __restrict__ mask,
                  float* __restrict__ scores) {
  const int lane = threadIdx.x & 63, wid = threadIdx.x >> 6;
  const int m0 = blockIdx.x * 64 + wid * 16;
  const int ar = lane & 15, ak = (lane >> 4) * 8;
  const int bb = m0 >> 11;
  const bf16_t* Wb = WaT + (PER_B ? (size_t)bb * H_ * D_ : 0);
  f32x4 acc = {};
  for (int k0 = 0; k0 < D_; k0 += 32) {
    bf16x8 a = *(const bf16x8*)&X[(size_t)(m0 + ar) * D_ + k0 + ak];
    bf16x8 b = *(const bf16x8*)&Wb[(size_t)ar * D_ + k0 + ak];
    acc = __builtin_amdgcn_mfma_f32_16x16x32_bf16(a, b, acc, 0, 0, 0);
  }
  const int h = lane & 15;
  const int srow = m0 + (lane >> 4) * 4;
  const int s0 = srow - bb * S_;
  const float bah = ba[h];
  f32x4 mv = *(const f32x4*)&mask[(size_t)bb * S_ + s0];
  f32x4 outv;
#pragma unroll
  for (int j = 0; j < 4; ++j)
    outv[j] = (acc[j] + bah) * SCALE + mv[j];
  *(f32x4*)&scores[((size_t)(bb * H_ + h)) * S_ + s0] = outv;
}

// ---------------------------------------------------------------------------
// softmax over each scores row -> normalized weights
// ---------------------------------------------------------------------------
__global__ __launch_bounds__(256)
void softmax_rows(const float* __restrict__ scores, float* __restrict__ wout) {
  __shared__ float rA[4], rB[4];
  const int tid = threadIdx.x, lane = tid & 63, wid = tid >> 6;
  const float* srow = scores + (size_t)blockIdx.x * S_;
  float* wrow = wout + (size_t)blockIdx.x * S_;
  f32x4 v0 = *(const f32x4*)&srow[tid * 4];
  f32x4 v1 = *(const f32x4*)&srow[1024 + tid * 4];
  float mx = fmaxf(fmaxf(fmaxf(v0[0], v0[1]), fmaxf(v0[2], v0[3])),
                   fmaxf(fmaxf(v1[0], v1[1]), fmaxf(v1[2], v1[3])));
#pragma unroll
  for (int o = 32; o; o >>= 1) mx = fmaxf(mx, __shfl_xor(mx, o));
  if (lane == 0) rA[wid] = mx;
  __syncthreads();
  mx = fmaxf(fmaxf(rA[0], rA[1]), fmaxf(rA[2], rA[3]));
  float sum = 0.f;
#pragma unroll
  for (int i = 0; i < 4; ++i) { v0[i] = __expf(v0[i] - mx); sum += v0[i]; }
#pragma unroll
  for (int i = 0; i < 4; ++i) { v1[i] = __expf(v1[i] - mx); sum += v1[i]; }
#pragma unroll
  for (int o = 32; o; o >>= 1) sum += __shfl_xor(sum, o);
  if (lane == 0) rB[wid] = sum;
  __syncthreads();
  sum = rB[0] + rB[1] + rB[2] + rB[3];
  const float inv = 1.0f / sum;
#pragma unroll
  for (int i = 0; i < 4; ++i) { v0[i] *= inv; v1[i] *= inv; }
  *(f32x4*)&wrow[tid * 4] = v0;
  *(f32x4*)&wrow[1024 + tid * 4] = v1;
}

// ---------------------------------------------------------------------------
// pool partials over 32-row chunks (coalesced bf16x8)
// ---------------------------------------------------------------------------
__global__ __launch_bounds__(256)
void pool_partial(const bf16_t* __restrict__ X, const float* __restrict__ w,
                  float* __restrict__ partials) {
  __shared__ float sm[2][1024];
  const int tid = threadIdx.x;
  const int chunk = blockIdx.x, b = blockIdx.y;
  const int s0 = chunk * 32;
  const int dc = (tid & 127) * 8;
  const int sp = tid >> 7;
  const int h = dc >> 6;
  const float* wrow = w + ((size_t)b * H_ + h) * S_ + s0;
  const bf16_t* Xb = X + ((size_t)b * S_ + s0) * D_ + dc;
  float acc[8] = {};
  for (int s = sp; s < 32; s += 2) {
    bf16x8 xv = *(const bf16x8*)&Xb[(size_t)s * D_];
    float wt = wrow[s];
#pragma unroll
    for (int j = 0; j < 8; ++j) acc[j] += wt * (float)xv[j];
  }
#pragma unroll
  for (int j = 0; j < 8; ++j) sm[sp][dc + j] = acc[j];
  __syncthreads();
  const int d0 = tid * 4;
  f32x4 r;
#pragma unroll
  for (int j = 0; j < 4; ++j) r[j] = sm[0][d0 + j] + sm[1][d0 + j];
  *(f32x4*)&partials[((size_t)chunk * B_ + b) * D_ + d0] = r;
}

// MODE 0: pq[idx] = sum; ALSO write wka_s[b][h][d] = bf16(pq * Wka[h][d])
// MODE 1: pk[idx] = sum * pq[idx]
template <int MODE>
__global__ __launch_bounds__(256)
void pool_reduce(const float* __restrict__ partials, const float* __restrict__ pq,
                 const bf16_t* __restrict__ WkaT, float* __restrict__ pooled,
                 bf16_t* __restrict__ wka_s) {
  const int idx = blockIdx.x * 256 + threadIdx.x;  // b*D + d
  float s = 0.f;
#pragma unroll 8
  for (int c = 0; c < 64; ++c) s += partials[(size_t)c * (B_ * D_) + idx];
  if (MODE == 1) s *= pq[idx];
  pooled[idx] = s;
  if (MODE == 0) {
    const int b = idx >> 10, d = idx & 1023;
#pragma unroll
    for (int h = 0; h < H_; ++h)
      wka_s[((size_t)b * H_ + h) * D_ + d] = (bf16_t)(s * (float)WkaT[h * D_ + d]);
  }
}

// ---------------------------------------------------------------------------
extern "C" void kernel_launch(void* const* d_in, const int* in_sizes, int n_in,
                              void* d_out, int out_size, void* d_ws, size_t ws_size,
                              hipStream_t stream) {
  const float* hs   = (const float*)d_in[0];
  const float* mask = (const float*)d_in[1];
  const float* Wq   = (const float*)d_in[2];
  const float* bq   = (const float*)d_in[3];
  const float* Wqa  = (const float*)d_in[4];
  const float* bqa  = (const float*)d_in[5];
  const float* Wk   = (const float*)d_in[6];
  const float* bk   = (const float*)d_in[7];
  const float* Wka  = (const float*)d_in[8];
  const float* bka  = (const float*)d_in[9];
  const float* Wt   = (const float*)d_in[10];
  const float* bt   = (const float*)d_in[11];

  char* ws = (char*)d_ws;
  float*  pq    = (float*)(ws + (64u << 10));
  float*  pk    = (float*)(ws + (128u << 10));
  bf16_t* wka_s = (bf16_t*)(ws + (256u << 10));
  bf16_t* WqaT  = (bf16_t*)(ws + (1u << 20));
  bf16_t* WkaT  = (bf16_t*)(ws + (1u << 20) + 32768);
  bf16_t* WqT   = (bf16_t*)(ws + (2u << 20));
  bf16_t* WkT   = (bf16_t*)(ws + (4u << 20));
  bf16_t* WtT   = (bf16_t*)(ws + (6u << 20));
  bf16_t* hsb   = (bf16_t*)(ws + (8u << 20));
  bf16_t* mq    = (bf16_t*)(ws + (8u << 20) + ((size_t)64 << 20));
  bf16_t* mk    = (bf16_t*)(ws + (8u << 20) + ((size_t)128 << 20));
  float* scores = (float*)(ws + (8u << 20) + ((size_t)192 << 20));
  float* wsm    = (float*)(ws + (8u << 20) + ((size_t)194 << 20));
  float* parts  = (float*)(ws + (8u << 20) + ((size_t)196 << 20));

  prep_all<<<dim3(16, 16, 20), 256, 0, stream>>>(Wq, Wk, Wt, Wqa, Wka, hs,
                                                 WqT, WkT, WtT, WqaT, WkaT, hsb);

  // mixed_q and mixed_k: 256x256 8-phase dual GEMM
  gemm_qk<<<1024, 512, 0, stream>>>(hsb, WqT, WkT, bq, bk, mq, mk);

  score_kernel<0><<<512, 256, 0, stream>>>(mq, WqaT, bqa, mask, scores);
  softmax_rows<<<256, 256, 0, stream>>>(scores, wsm);
  pool_partial<<<dim3(64, 16), 256, 0, stream>>>(mq, wsm, parts);
  pool_reduce<0><<<64, 256, 0, stream>>>(parts, nullptr, WkaT, pq, wka_s);

  score_kernel<1><<<512, 256, 0, stream>>>(mk, wka_s, bka, mask, scores);
  softmax_rows<<<256, 256, 0, stream>>>(scores, wsm);
  pool_partial<<<dim3(64, 16), 256, 0, stream>>>(mk, wsm, parts);
  pool_reduce<1><<<64, 256, 0, stream>>>(parts, pq, nullptr, pk, nullptr);

  // out = (mq * pk) @ Wt + bt + mixed_q
  gemm_out<<<2048, 256, 0, stream>>>(mq, WtT, bt, (float*)d_out, mq, pk);
}

// Round 16
// 357.441 us; speedup vs baseline: 1.2342x; 1.0224x over previous
//
#include <hip/hip_runtime.h>
#include <hip/hip_bf16.h>
#include <stdint.h>

#define D_ 1024
#define H_ 16
#define DH_ 64
#define S_ 2048
#define B_ 16
static constexpr float SCALE = 0.125f;  // 1/sqrt(64)

typedef __bf16 bf16_t;
typedef __bf16 bf16x8 __attribute__((ext_vector_type(8)));
typedef __bf16 bf16x4 __attribute__((ext_vector_type(4)));
typedef float  f32x4  __attribute__((ext_vector_type(4)));

__device__ __forceinline__ void llds16(const void* g, void* l) {
  __builtin_amdgcn_global_load_lds(
      (const __attribute__((address_space(1))) void*)g,
      (__attribute__((address_space(3))) void*)l, 16, 0, 0);
}

// ---------------------------------------------------------------------------
// prep_all: one launch for all input preprocessing.
// ---------------------------------------------------------------------------
__global__ __launch_bounds__(256)
void prep_all(const float* __restrict__ Wq, const float* __restrict__ Wk,
              const float* __restrict__ Wt, const float* __restrict__ Wqa,
              const float* __restrict__ Wka, const float* __restrict__ hs,
              bf16_t* __restrict__ WqT, bf16_t* __restrict__ WkT,
              bf16_t* __restrict__ WtT, bf16_t* __restrict__ WqaT,
              bf16_t* __restrict__ WkaT, bf16_t* __restrict__ hsb) {
  __shared__ bf16_t t[64][65];
  const int z = blockIdx.z;
  const int tid = threadIdx.x;
  if (z < 3) {
    const float* src = (z == 0) ? Wq : (z == 1) ? Wk : Wt;
    bf16_t* dst      = (z == 0) ? WqT : (z == 1) ? WkT : WtT;
    const int n0 = blockIdx.x * 64, k0 = blockIdx.y * 64;
    const int r = tid >> 4, c4 = (tid & 15) * 4;
#pragma unroll
    for (int p = 0; p < 4; ++p) {
      int row = p * 16 + r;
      f32x4 f = *(const f32x4*)&src[(size_t)(k0 + row) * 1024 + n0 + c4];
#pragma unroll
      for (int i = 0; i < 4; ++i) t[row][c4 + i] = (bf16_t)f[i];
    }
    __syncthreads();
#pragma unroll
    for (int p = 0; p < 4; ++p) {
      int row = p * 16 + r;
      bf16x4 v;
#pragma unroll
      for (int i = 0; i < 4; ++i) v[i] = t[c4 + i][row];
      *(bf16x4*)&dst[(size_t)(n0 + row) * 1024 + k0 + c4] = v;
    }
  } else if (z == 3) {
    int g = (blockIdx.y * 16 + blockIdx.x) * 256 + tid;
    if (g < 2048) {
      const float* src = (g < 1024) ? Wqa : Wka;
      bf16_t* dst      = (g < 1024) ? WqaT : WkaT;
      int k = g & 1023;
#pragma unroll
      for (int h = 0; h < H_; ++h) dst[h * 1024 + k] = (bf16_t)src[k * H_ + h];
    }
  } else {
    const int slice = z - 4;
    const int fb = blockIdx.y * 16 + blockIdx.x;
    const size_t tbase = ((size_t)slice * 256 + fb) * 256 + tid;
#pragma unroll
    for (int i = 0; i < 4; ++i) {
      size_t e = (tbase + (size_t)i * 1048576) * 8;
      f32x4 a = *(const f32x4*)&hs[e];
      f32x4 b = *(const f32x4*)&hs[e + 4];
      bf16x8 o;
#pragma unroll
      for (int j = 0; j < 4; ++j) { o[j] = (bf16_t)a[j]; o[4 + j] = (bf16_t)b[j]; }
      *(bf16x8*)&hsb[e] = o;
    }
  }
}

// ---------------------------------------------------------------------------
// Dual-N 256x256 8-phase GEMM (r15 structure, refcheck'd). Swizzle FIX:
// rotation (r>>1)&3 (period 8 -> free 2-way aliasing; r15's (r&3) period-4
// was a 4-way conflict, 16.8M SQ_LDS_BANK_CONFLICT).
// ---------------------------------------------------------------------------
__global__ __launch_bounds__(512, 1)
void gemm_qk(const bf16_t* __restrict__ A, const bf16_t* __restrict__ WqT,
             const bf16_t* __restrict__ WkT, const float* __restrict__ bq,
             const float* __restrict__ bk, bf16_t* __restrict__ mq,
             bf16_t* __restrict__ mk) {
  constexpr int K = 1024, N = 1024;
  __shared__ __align__(16) bf16_t lds[2][2][2][256 * 32];
  const int tid = threadIdx.x;
  const int lane = tid & 63, wid = tid >> 6;
  const int wm = wid >> 2, wn = wid & 3;

  const int wgid = (blockIdx.x & 7) * 128 + (blockIdx.x >> 3);
  const int m0 = (wgid >> 3) * 256;
  const int nsel = wgid & 7;
  const int n0 = (nsel & 3) * 256;
  const bf16_t* BT = (nsel < 4) ? WqT : WkT;
  const float* bias = (nsel < 4) ? bq : bk;
  bf16_t* Cout = (nsel < 4) ? mq : mk;

  int srow[2], scol[2];
#pragma unroll
  for (int ld = 0; ld < 2; ++ld) {
    int c = ld * 512 + tid;
    srow[ld] = c >> 2;
    scol[ld] = (((c & 3) - ((srow[ld] >> 1) & 3)) & 3) * 8;
  }

  const int ar = lane & 15;
  const int kc = lane >> 4;

  f32x4 acc[8][4] = {};

#define STAGE_(MAT, KH, KOFF, NXT)                                             \
  {                                                                            \
    const bf16_t* srcb = (MAT == 0) ? A : BT;                                  \
    const int rb = (MAT == 0) ? m0 : n0;                                       \
    _Pragma("unroll")                                                          \
    for (int ld = 0; ld < 2; ++ld) {                                           \
      llds16(srcb + (size_t)(rb + srow[ld]) * K + (KOFF) + (KH) * 32 + scol[ld], \
             &lds[NXT][MAT][KH][(ld * 512 + tid) * 8]);                        \
    }                                                                          \
  }

#define COMPUTE_(KH, MH, CUR)                                                  \
  {                                                                            \
    bf16x8 af[4], bg[4];                                                       \
    _Pragma("unroll")                                                          \
    for (int mm = 0; mm < 4; ++mm) {                                           \
      int r = wm * 128 + ((MH) * 4 + mm) * 16 + ar;                            \
      int slot = (kc + ((r >> 1) & 3)) & 3;                                    \
      af[mm] = *(const bf16x8*)&lds[CUR][0][KH][r * 32 + slot * 8];            \
    }                                                                          \
    _Pragma("unroll")                                                          \
    for (int nn = 0; nn < 4; ++nn) {                                           \
      int r = wn * 64 + nn * 16 + ar;                                          \
      int slot = (kc + ((r >> 1) & 3)) & 3;                                    \
      bg[nn] = *(const bf16x8*)&lds[CUR][1][KH][r * 32 + slot * 8];            \
    }                                                                          \
    __builtin_amdgcn_s_setprio(1);                                             \
    _Pragma("unroll")                                                          \
    for (int mm = 0; mm < 4; ++mm)                                             \
      _Pragma("unroll")                                                        \
      for (int nn = 0; nn < 4; ++nn)                                           \
        acc[(MH) * 4 + mm][nn] = __builtin_amdgcn_mfma_f32_16x16x32_bf16(      \
            af[mm], bg[nn], acc[(MH) * 4 + mm][nn], 0, 0, 0);                  \
    __builtin_amdgcn_s_setprio(0);                                             \
  }

  STAGE_(0, 0, 0, 0); STAGE_(1, 0, 0, 0); STAGE_(0, 1, 0, 0); STAGE_(1, 1, 0, 0);

#pragma unroll 1
  for (int t = 0; t < 15; ++t) {
    const int cur = t & 1, nxt = cur ^ 1;
    const int koff = (t + 1) * 64;
    STAGE_(0, 0, koff, nxt);
    asm volatile("s_waitcnt vmcnt(6)" ::: "memory");
    __builtin_amdgcn_s_barrier();
    COMPUTE_(0, 0, cur);
    STAGE_(1, 0, koff, nxt);
    COMPUTE_(0, 1, cur);
    STAGE_(0, 1, koff, nxt);
    asm volatile("s_waitcnt vmcnt(6)" ::: "memory");
    __builtin_amdgcn_s_barrier();
    COMPUTE_(1, 0, cur);
    STAGE_(1, 1, koff, nxt);
    COMPUTE_(1, 1, cur);
  }
  asm volatile("s_waitcnt vmcnt(4)" ::: "memory");
  __builtin_amdgcn_s_barrier();
  COMPUTE_(0, 0, 1);
  COMPUTE_(0, 1, 1);
  asm volatile("s_waitcnt vmcnt(0)" ::: "memory");
  __builtin_amdgcn_s_barrier();
  COMPUTE_(1, 0, 1);
  COMPUTE_(1, 1, 1);
#undef STAGE_
#undef COMPUTE_

  __syncthreads();

  float* st = (float*)&lds[0][0][0][0] + wid * (16 * 68);
  const int erow = lane >> 2;
  const int ecol = (lane & 3) * 16;
  const int gcb = n0 + wn * 64;
  const int qrow = (lane >> 4) * 4;
  const int qcol = lane & 15;
  f32x4 bb[4];
#pragma unroll
  for (int q = 0; q < 4; ++q) bb[q] = *(const f32x4*)&bias[gcb + ecol + q * 4];
#pragma unroll
  for (int m = 0; m < 8; ++m) {
#pragma unroll
    for (int n = 0; n < 4; ++n)
#pragma unroll
      for (int j = 0; j < 4; ++j)
        st[(qrow + j) * 68 + n * 16 + qcol] = acc[m][n][j];
    asm volatile("s_waitcnt lgkmcnt(0)" ::: "memory");
    __builtin_amdgcn_sched_barrier(0);
    const int grow = m0 + wm * 128 + m * 16 + erow;
    f32x4 v[4];
#pragma unroll
    for (int q = 0; q < 4; ++q) v[q] = *(f32x4*)&st[erow * 68 + ecol + q * 4];
#pragma unroll
    for (int q = 0; q < 4; ++q)
#pragma unroll
      for (int i = 0; i < 4; ++i) v[q][i] += bb[q][i];
    bf16x8 o0, o1;
#pragma unroll
    for (int i = 0; i < 4; ++i) { o0[i] = (bf16_t)v[0][i]; o0[4 + i] = (bf16_t)v[1][i]; }
#pragma unroll
    for (int i = 0; i < 4; ++i) { o1[i] = (bf16_t)v[2][i]; o1[4 + i] = (bf16_t)v[3][i]; }
    bf16_t* op = Cout + (size_t)grow * N + gcb + ecol;
    *(bf16x8*)&op[0] = o0;
    *(bf16x8*)&op[8] = o1;
  }
}

// ---------------------------------------------------------------------------
// wt_s[b][n][k] = bf16(pk[b,k] * WtT[n,k])  (folds the weighted-modulate into
// B so gemm_out8 is a PURE 8-phase GEMM; 32MB, ~8us)
// ---------------------------------------------------------------------------
__global__ __launch_bounds__(256)
void wt_scale(const bf16_t* __restrict__ WtT, const float* __restrict__ pk,
              bf16_t* __restrict__ wt_s) {
  size_t e = ((size_t)blockIdx.x * 256 + threadIdx.x) * 8;
  const int b = (int)(e >> 20);
  const int nk = (int)(e & 1048575);
  const int k = nk & 1023;
  bf16x8 w = *(const bf16x8*)&WtT[nk];
  const float* pp = &pk[b * D_ + k];
  f32x4 p0 = *(const f32x4*)pp;
  f32x4 p1 = *(const f32x4*)(pp + 4);
  bf16x8 o;
#pragma unroll
  for (int i = 0; i < 4; ++i) {
    o[i]     = (bf16_t)((float)w[i] * p0[i]);
    o[4 + i] = (bf16_t)((float)w[4 + i] * p1[i]);
  }
  *(bf16x8*)&wt_s[e] = o;
}

// ---------------------------------------------------------------------------
// Final GEMM, 8-phase clone: out = mq @ wt_s[b] + bt + resid(mq) -> f32
// ---------------------------------------------------------------------------
__global__ __launch_bounds__(512, 1)
void gemm_out8(const bf16_t* __restrict__ A, const bf16_t* __restrict__ WtS,
               const float* __restrict__ bias, float* __restrict__ Cout,
               const bf16_t* __restrict__ resid) {
  constexpr int K = 1024, N = 1024;
  __shared__ __align__(16) bf16_t lds[2][2][2][256 * 32];
  const int tid = threadIdx.x;
  const int lane = tid & 63, wid = tid >> 6;
  const int wm = wid >> 2, wn = wid & 3;

  // nwg=512, 512%8==0
  const int wgid = (blockIdx.x & 7) * 64 + (blockIdx.x >> 3);
  const int m0 = (wgid >> 2) * 256;
  const int n0 = (wgid & 3) * 256;
  const bf16_t* BT = WtS + ((size_t)(m0 >> 11) << 20);  // per-b B panel

  int srow[2], scol[2];
#pragma unroll
  for (int ld = 0; ld < 2; ++ld) {
    int c = ld * 512 + tid;
    srow[ld] = c >> 2;
    scol[ld] = (((c & 3) - ((srow[ld] >> 1) & 3)) & 3) * 8;
  }

  const int ar = lane & 15;
  const int kc = lane >> 4;

  f32x4 acc[8][4] = {};

#define STAGE2_(MAT, KH, KOFF, NXT)                                            \
  {                                                                            \
    const bf16_t* srcb = (MAT == 0) ? A : BT;                                  \
    const int rb = (MAT == 0) ? m0 : n0;                                       \
    _Pragma("unroll")                                                          \
    for (int ld = 0; ld < 2; ++ld) {                                           \
      llds16(srcb + (size_t)(rb + srow[ld]) * K + (KOFF) + (KH) * 32 + scol[ld], \
             &lds[NXT][MAT][KH][(ld * 512 + tid) * 8]);                        \
    }                                                                          \
  }

#define COMPUTE2_(KH, MH, CUR)                                                 \
  {                                                                            \
    bf16x8 af[4], bg[4];                                                       \
    _Pragma("unroll")                                                          \
    for (int mm = 0; mm < 4; ++mm) {                                           \
      int r = wm * 128 + ((MH) * 4 + mm) * 16 + ar;                            \
      int slot = (kc + ((r >> 1) & 3)) & 3;                                    \
      af[mm] = *(const bf16x8*)&lds[CUR][0][KH][r * 32 + slot * 8];            \
    }                                                                          \
    _Pragma("unroll")                                                          \
    for (int nn = 0; nn < 4; ++nn) {                                           \
      int r = wn * 64 + nn * 16 + ar;                                          \
      int slot = (kc + ((r >> 1) & 3)) & 3;                                    \
      bg[nn] = *(const bf16x8*)&lds[CUR][1][KH][r * 32 + slot * 8];            \
    }                                                                          \
    __builtin_amdgcn_s_setprio(1);                                             \
    _Pragma("unroll")                                                          \
    for (int mm = 0; mm < 4; ++mm)                                             \
      _Pragma("unroll")                                                        \
      for (int nn = 0; nn < 4; ++nn)                                           \
        acc[(MH) * 4 + mm][nn] = __builtin_amdgcn_mfma_f32_16x16x32_bf16(      \
            af[mm], bg[nn], acc[(MH) * 4 + mm][nn], 0, 0, 0);                  \
    __builtin_amdgcn_s_setprio(0);                                             \
  }

  STAGE2_(0, 0, 0, 0); STAGE2_(1, 0, 0, 0); STAGE2_(0, 1, 0, 0); STAGE2_(1, 1, 0, 0);

#pragma unroll 1
  for (int t = 0; t < 15; ++t) {
    const int cur = t & 1, nxt = cur ^ 1;
    const int koff = (t + 1) * 64;
    STAGE2_(0, 0, koff, nxt);
    asm volatile("s_waitcnt vmcnt(6)" ::: "memory");
    __builtin_amdgcn_s_barrier();
    COMPUTE2_(0, 0, cur);
    STAGE2_(1, 0, koff, nxt);
    COMPUTE2_(0, 1, cur);
    STAGE2_(0, 1, koff, nxt);
    asm volatile("s_waitcnt vmcnt(6)" ::: "memory");
    __builtin_amdgcn_s_barrier();
    COMPUTE2_(1, 0, cur);
    STAGE2_(1, 1, koff, nxt);
    COMPUTE2_(1, 1, cur);
  }
  asm volatile("s_waitcnt vmcnt(4)" ::: "memory");
  __builtin_amdgcn_s_barrier();
  COMPUTE2_(0, 0, 1);
  COMPUTE2_(0, 1, 1);
  asm volatile("s_waitcnt vmcnt(0)" ::: "memory");
  __builtin_amdgcn_s_barrier();
  COMPUTE2_(1, 0, 1);
  COMPUTE2_(1, 1, 1);
#undef STAGE2_
#undef COMPUTE2_

  __syncthreads();

  float* st = (float*)&lds[0][0][0][0] + wid * (16 * 68);
  const int erow = lane >> 2;
  const int ecol = (lane & 3) * 16;
  const int gcb = n0 + wn * 64;
  const int qrow = (lane >> 4) * 4;
  const int qcol = lane & 15;
  f32x4 bb[4];
#pragma unroll
  for (int q = 0; q < 4; ++q) bb[q] = *(const f32x4*)&bias[gcb + ecol + q * 4];
#pragma unroll
  for (int m = 0; m < 8; ++m) {
#pragma unroll
    for (int n = 0; n < 4; ++n)
#pragma unroll
      for (int j = 0; j < 4; ++j)
        st[(qrow + j) * 68 + n * 16 + qcol] = acc[m][n][j];
    asm volatile("s_waitcnt lgkmcnt(0)" ::: "memory");
    __builtin_amdgcn_sched_barrier(0);
    const int grow = m0 + wm * 128 + m * 16 + erow;
    f32x4 v[4];
#pragma unroll
    for (int q = 0; q < 4; ++q) v[q] = *(f32x4*)&st[erow * 68 + ecol + q * 4];
#pragma unroll
    for (int q = 0; q < 4; ++q)
#pragma unroll
      for (int i = 0; i < 4; ++i) v[q][i] += bb[q][i];
    bf16x8 r0 = *(const bf16x8*)&resid[(size_t)grow * N + gcb + ecol];
    bf16x8 r1 = *(const bf16x8*)&resid[(size_t)grow * N + gcb + ecol + 8];
#pragma unroll
    for (int i = 0; i < 4; ++i) { v[0][i] += (float)r0[i]; v[1][i] += (float)r0[4 + i]; }
#pragma unroll
    for (int i = 0; i < 4; ++i) { v[2][i] += (float)r1[i]; v[3][i] += (float)r1[4 + i]; }
    float* op = Cout + (size_t)grow * N + gcb + ecol;
#pragma unroll
    for (int q = 0; q < 4; ++q) *(f32x4*)&op[q * 4] = v[q];
  }
}

// ---------------------------------------------------------------------------
// scores[b*H+h][s] = (X[b,s,:] . Wa[h,:] + ba[h]) * SCALE + mask[b][s]
// ---------------------------------------------------------------------------
template <int PER_B>
__global__ __launch_bounds__(256)
void score_kernel(const bf16_t* __restrict__ X, const bf16_t* __restrict__ WaT,
                  const float* __restrict__ ba, const float* __restrict__ mask,
                  float* __restrict__ scores) {
  const int lane = threadIdx.x & 63, wid = threadIdx.x >> 6;
  const int m0 = blockIdx.x * 64 + wid * 16;
  const int ar = lane & 15, ak = (lane >> 4) * 8;
  const int bb = m0 >> 11;
  const bf16_t* Wb = WaT + (PER_B ? (size_t)bb * H_ * D_ : 0);
  f32x4 acc = {};
  for (int k0 = 0; k0 < D_; k0 += 32) {
    bf16x8 a = *(const bf16x8*)&X[(size_t)(m0 + ar) * D_ + k0 + ak];
    bf16x8 b = *(const bf16x8*)&Wb[(size_t)ar * D_ + k0 + ak];
    acc = __builtin_amdgcn_mfma_f32_16x16x32_bf16(a, b, acc, 0, 0, 0);
  }
  const int h = lane & 15;
  const int srow = m0 + (lane >> 4) * 4;
  const int s0 = srow - bb * S_;
  const float bah = ba[h];
  f32x4 mv = *(const f32x4*)&mask[(size_t)bb * S_ + s0];
  f32x4 outv;
#pragma unroll
  for (int j = 0; j < 4; ++j)
    outv[j] = (acc[j] + bah) * SCALE + mv[j];
  *(f32x4*)&scores[((size_t)(bb * H_ + h)) * S_ + s0] = outv;
}

// ---------------------------------------------------------------------------
// softmax over each scores row -> normalized weights
// ---------------------------------------------------------------------------
__global__ __launch_bounds__(256)
void softmax_rows(const float* __restrict__ scores, float* __restrict__ wout) {
  __shared__ float rA[4], rB[4];
  const int tid = threadIdx.x, lane = tid & 63, wid = tid >> 6;
  const float* srow = scores + (size_t)blockIdx.x * S_;
  float* wrow = wout + (size_t)blockIdx.x * S_;
  f32x4 v0 = *(const f32x4*)&srow[tid * 4];
  f32x4 v1 = *(const f32x4*)&srow[1024 + tid * 4];
  float mx = fmaxf(fmaxf(fmaxf(v0[0], v0[1]), fmaxf(v0[2], v0[3])),
                   fmaxf(fmaxf(v1[0], v1[1]), fmaxf(v1[2], v1[3])));
#pragma unroll
  for (int o = 32; o; o >>= 1) mx = fmaxf(mx, __shfl_xor(mx, o));
  if (lane == 0) rA[wid] = mx;
  __syncthreads();
  mx = fmaxf(fmaxf(rA[0], rA[1]), fmaxf(rA[2], rA[3]));
  float sum = 0.f;
#pragma unroll
  for (int i = 0; i < 4; ++i) { v0[i] = __expf(v0[i] - mx); sum += v0[i]; }
#pragma unroll
  for (int i = 0; i < 4; ++i) { v1[i] = __expf(v1[i] - mx); sum += v1[i]; }
#pragma unroll
  for (int o = 32; o; o >>= 1) sum += __shfl_xor(sum, o);
  if (lane == 0) rB[wid] = sum;
  __syncthreads();
  sum = rB[0] + rB[1] + rB[2] + rB[3];
  const float inv = 1.0f / sum;
#pragma unroll
  for (int i = 0; i < 4; ++i) { v0[i] *= inv; v1[i] *= inv; }
  *(f32x4*)&wrow[tid * 4] = v0;
  *(f32x4*)&wrow[1024 + tid * 4] = v1;
}

// ---------------------------------------------------------------------------
// pool partials over 32-row chunks (coalesced bf16x8)
// ---------------------------------------------------------------------------
__global__ __launch_bounds__(256)
void pool_partial(const bf16_t* __restrict__ X, const float* __restrict__ w,
                  float* __restrict__ partials) {
  __shared__ float sm[2][1024];
  const int tid = threadIdx.x;
  const int chunk = blockIdx.x, b = blockIdx.y;
  const int s0 = chunk * 32;
  const int dc = (tid & 127) * 8;
  const int sp = tid >> 7;
  const int h = dc >> 6;
  const float* wrow = w + ((size_t)b * H_ + h) * S_ + s0;
  const bf16_t* Xb = X + ((size_t)b * S_ + s0) * D_ + dc;
  float acc[8] = {};
  for (int s = sp; s < 32; s += 2) {
    bf16x8 xv = *(const bf16x8*)&Xb[(size_t)s * D_];
    float wt = wrow[s];
#pragma unroll
    for (int j = 0; j < 8; ++j) acc[j] += wt * (float)xv[j];
  }
#pragma unroll
  for (int j = 0; j < 8; ++j) sm[sp][dc + j] = acc[j];
  __syncthreads();
  const int d0 = tid * 4;
  f32x4 r;
#pragma unroll
  for (int j = 0; j < 4; ++j) r[j] = sm[0][d0 + j] + sm[1][d0 + j];
  *(f32x4*)&partials[((size_t)chunk * B_ + b) * D_ + d0] = r;
}

// MODE 0: pq[idx] = sum; ALSO write wka_s[b][h][d] = bf16(pq * Wka[h][d])
// MODE 1: pk[idx] = sum * pq[idx]
template <int MODE>
__global__ __launch_bounds__(256)
void pool_reduce(const float* __restrict__ partials, const float* __restrict__ pq,
                 const bf16_t* __restrict__ WkaT, float* __restrict__ pooled,
                 bf16_t* __restrict__ wka_s) {
  const int idx = blockIdx.x * 256 + threadIdx.x;
  float s = 0.f;
#pragma unroll 8
  for (int c = 0; c < 64; ++c) s += partials[(size_t)c * (B_ * D_) + idx];
  if (MODE == 1) s *= pq[idx];
  pooled[idx] = s;
  if (MODE == 0) {
    const int b = idx >> 10, d = idx & 1023;
#pragma unroll
    for (int h = 0; h < H_; ++h)
      wka_s[((size_t)b * H_ + h) * D_ + d] = (bf16_t)(s * (float)WkaT[h * D_ + d]);
  }
}

// ---------------------------------------------------------------------------
extern "C" void kernel_launch(void* const* d_in, const int* in_sizes, int n_in,
                              void* d_out, int out_size, void* d_ws, size_t ws_size,
                              hipStream_t stream) {
  const float* hs   = (const float*)d_in[0];
  const float* mask = (const float*)d_in[1];
  const float* Wq   = (const float*)d_in[2];
  const float* bq   = (const float*)d_in[3];
  const float* Wqa  = (const float*)d_in[4];
  const float* bqa  = (const float*)d_in[5];
  const float* Wk   = (const float*)d_in[6];
  const float* bk   = (const float*)d_in[7];
  const float* Wka  = (const float*)d_in[8];
  const float* bka  = (const float*)d_in[9];
  const float* Wt   = (const float*)d_in[10];
  const float* bt   = (const float*)d_in[11];

  char* ws = (char*)d_ws;
  float*  pq    = (float*)(ws + (64u << 10));
  float*  pk    = (float*)(ws + (128u << 10));
  bf16_t* wka_s = (bf16_t*)(ws + (256u << 10));
  bf16_t* WqaT  = (bf16_t*)(ws + (1u << 20));
  bf16_t* WkaT  = (bf16_t*)(ws + (1u << 20) + 32768);
  bf16_t* WqT   = (bf16_t*)(ws + (2u << 20));
  bf16_t* WkT   = (bf16_t*)(ws + (4u << 20));
  bf16_t* WtT   = (bf16_t*)(ws + (6u << 20));
  bf16_t* hsb   = (bf16_t*)(ws + (8u << 20));
  bf16_t* mq    = (bf16_t*)(ws + (8u << 20) + ((size_t)64 << 20));
  bf16_t* mk    = (bf16_t*)(ws + (8u << 20) + ((size_t)128 << 20));
  float* scores = (float*)(ws + (8u << 20) + ((size_t)192 << 20));
  float* wsm    = (float*)(ws + (8u << 20) + ((size_t)194 << 20));
  float* parts  = (float*)(ws + (8u << 20) + ((size_t)196 << 20));
  bf16_t* wt_s  = (bf16_t*)(ws + (8u << 20) + ((size_t)208 << 20));  // 32 MB

  prep_all<<<dim3(16, 16, 20), 256, 0, stream>>>(Wq, Wk, Wt, Wqa, Wka, hs,
                                                 WqT, WkT, WtT, WqaT, WkaT, hsb);

  // mixed_q and mixed_k: 256x256 8-phase dual GEMM (swizzle-fixed)
  gemm_qk<<<1024, 512, 0, stream>>>(hsb, WqT, WkT, bq, bk, mq, mk);

  score_kernel<0><<<512, 256, 0, stream>>>(mq, WqaT, bqa, mask, scores);
  softmax_rows<<<256, 256, 0, stream>>>(scores, wsm);
  pool_partial<<<dim3(64, 16), 256, 0, stream>>>(mq, wsm, parts);
  pool_reduce<0><<<64, 256, 0, stream>>>(parts, nullptr, WkaT, pq, wka_s);

  score_kernel<1><<<512, 256, 0, stream>>>(mk, wka_s, bka, mask, scores);
  softmax_rows<<<256, 256, 0, stream>>>(scores, wsm);
  pool_partial<<<dim3(64, 16), 256, 0, stream>>>(mk, wsm, parts);
  pool_reduce<1><<<64, 256, 0, stream>>>(parts, pq, nullptr, pk, nullptr);

  // fold pk into Wt (per-b), then pure 8-phase final GEMM
  wt_scale<<<8192, 256, 0, stream>>>(WtT, pk, wt_s);
  gemm_out8<<<512, 512, 0, stream>>>(mq, wt_s, bt, (float*)d_out, mq);
}